// Round 1
// baseline (559.944 us; speedup 1.0000x reference)
//
#include <hip/hip_runtime.h>
#include <math.h>

#define B_ 8
#define N_ 224
#define E_ 64
#define M_ 128
#define S_ 32
#define D_ 256
#define IN_ 300
#define R_ 5
#define H_ 4
#define DK_ 64
#define OUTROWS (N_ + 2 * E_ * E_)   // 8416

// ---------------- denoms[b,n] = 1 + sum_{r,m} adj[b,r,n,m] ----------------
__global__ void denoms_kernel(const float* __restrict__ adj, float* __restrict__ den) {
    int bn = blockIdx.x;
    int b = bn / N_, n = bn % N_;
    __shared__ float red[256];
    float s = 0.f;
    for (int rm = threadIdx.x; rm < R_ * N_; rm += 256) {
        int r = rm / N_, m = rm % N_;
        s += adj[(((size_t)(b * R_ + r)) * N_ + n) * N_ + m];
    }
    red[threadIdx.x] = s;
    __syncthreads();
    for (int st = 128; st > 0; st >>= 1) {
        if (threadIdx.x < st) red[threadIdx.x] += red[threadIdx.x + st];
        __syncthreads();
    }
    if (threadIdx.x == 0) den[bn] = red[0] + 1.0f;
}

// ---------------- generic tiled matmul C = A@B (+bias), z-sliced ----------------
// block 16x16 threads, 32x32 output tile, 2x2 per thread
__global__ void matmul_bias(const float* __restrict__ A, long long azs, int lda,
                            const float* __restrict__ Bm, long long bzs, int ldb,
                            float* __restrict__ C, long long czs, int ldc,
                            const float* __restrict__ bias, long long biaszs,
                            int Mr, int Nc, int K) {
    A  += (size_t)blockIdx.z * azs;
    Bm += (size_t)blockIdx.z * bzs;
    C  += (size_t)blockIdx.z * czs;
    if (bias) bias += (size_t)blockIdx.z * biaszs;
    __shared__ float As[32][33], Bs[32][33];
    int tx = threadIdx.x, ty = threadIdx.y, tid = ty * 16 + tx;
    int row0 = blockIdx.y * 32, col0 = blockIdx.x * 32;
    float acc[2][2] = {};
    for (int k0 = 0; k0 < K; k0 += 32) {
        for (int e = tid; e < 32 * 32; e += 256) {
            int r = e >> 5, c = e & 31;
            int gr = row0 + r, gc = k0 + c;
            As[r][c] = (gr < Mr && gc < K) ? A[(size_t)gr * lda + gc] : 0.f;
            int br = k0 + r, bc = col0 + c;
            Bs[r][c] = (br < K && bc < Nc) ? Bm[(size_t)br * ldb + bc] : 0.f;
        }
        __syncthreads();
#pragma unroll
        for (int kk = 0; kk < 32; ++kk) {
            float a0 = As[ty * 2][kk], a1 = As[ty * 2 + 1][kk];
            float b0 = Bs[kk][tx * 2], b1 = Bs[kk][tx * 2 + 1];
            acc[0][0] += a0 * b0; acc[0][1] += a0 * b1;
            acc[1][0] += a1 * b0; acc[1][1] += a1 * b1;
        }
        __syncthreads();
    }
    for (int i = 0; i < 2; ++i) {
        int gr = row0 + ty * 2 + i;
        if (gr >= Mr) continue;
        for (int j = 0; j < 2; ++j) {
            int gc = col0 + tx * 2 + j;
            if (gc >= Nc) continue;
            float v = acc[i][j];
            if (bias) v += bias[gc];
            C[(size_t)gr * ldc + gc] = v;
        }
    }
}

// --------- AxW = sum_r adj[b,r] @ xW[r,b]; out = relu((AxW + t)/den) ---------
// xW layout (R,B,N,D). grid: (D/32, N/32, B)
__global__ void axw_epilogue(const float* __restrict__ adj, const float* __restrict__ xW,
                             const float* __restrict__ t, const float* __restrict__ den,
                             float* __restrict__ out, long long out_bstride) {
    int b = blockIdx.z;
    int row0 = blockIdx.y * 32;   // n
    int col0 = blockIdx.x * 32;   // d
    __shared__ float As[32][33], Bs[32][33];
    int tx = threadIdx.x, ty = threadIdx.y, tid = ty * 16 + tx;
    float acc[2][2] = {};
    for (int r = 0; r < R_; ++r) {
        const float* adjb = adj + ((size_t)(b * R_ + r)) * N_ * N_;
        const float* xwb  = xW + ((size_t)(r * B_ + b)) * N_ * D_;
        for (int m0 = 0; m0 < N_; m0 += 32) {
            for (int e = tid; e < 32 * 32; e += 256) {
                int rr = e >> 5, cc = e & 31;
                As[rr][cc] = adjb[(size_t)(row0 + rr) * N_ + m0 + cc];
                Bs[rr][cc] = xwb[(size_t)(m0 + rr) * D_ + col0 + cc];
            }
            __syncthreads();
#pragma unroll
            for (int kk = 0; kk < 32; ++kk) {
                float a0 = As[ty * 2][kk], a1 = As[ty * 2 + 1][kk];
                float b0 = Bs[kk][tx * 2], b1 = Bs[kk][tx * 2 + 1];
                acc[0][0] += a0 * b0; acc[0][1] += a0 * b1;
                acc[1][0] += a1 * b0; acc[1][1] += a1 * b1;
            }
            __syncthreads();
        }
    }
    for (int i = 0; i < 2; ++i) {
        int n = row0 + ty * 2 + i;
        float dn = den[b * N_ + n];
        for (int j = 0; j < 2; ++j) {
            int d = col0 + tx * 2 + j;
            float v = acc[i][j] + t[((size_t)b * N_ + n) * D_ + d];
            v /= dn;
            out[(size_t)b * out_bstride + (size_t)n * D_ + d] = v > 0.f ? v : 0.f;
        }
    }
}

// ---------------- small gathers ----------------
__global__ void gather_ents(const float* __restrict__ outbuf, float* __restrict__ ents) {
    int idx = blockIdx.x * 256 + threadIdx.x;
    if (idx >= B_ * E_ * D_) return;
    int b = idx / (E_ * D_);
    int r = idx % (E_ * D_);
    ents[idx] = outbuf[(size_t)b * OUTROWS * D_ + r];
}
__global__ void gather_msr(const float* __restrict__ sentences, const int* __restrict__ sid,
                           float* __restrict__ msr) {
    int idx = blockIdx.x * 256 + threadIdx.x;
    if (idx >= B_ * M_ * D_) return;
    int bm = idx / D_, d = idx % D_;
    msr[idx] = sentences[(size_t)sid[bm] * D_ + d];
}
__global__ void mention_lists(const int* __restrict__ eid, int* __restrict__ cnt,
                              int* __restrict__ mlist) {
    int t = blockIdx.x * blockDim.x + threadIdx.x;
    if (t >= B_ * E_) return;
    int b = t / E_, i = t % E_;
    int c = 0;
    for (int m = 0; m < M_; ++m)
        if (eid[b * M_ + m] == i) mlist[(size_t)t * M_ + c++] = m;
    cnt[t] = c;
}

// ------------- per (b, masked-entity) attention combine -------------
// For rep_h (transposed=0): block me = i (mask), loop q = j (query), row = me*E+q.
// For rep_t (transposed=1): block me = j (mask), loop q = i (query), row = q*E+me.
__global__ __launch_bounds__(256) void combine_kernel(
    const float* __restrict__ Q, const float* __restrict__ K,
    const float* __restrict__ VW, const int* __restrict__ cnt,
    const int* __restrict__ mlist, float* __restrict__ out,
    int baserow, int transposed) {
    int b = blockIdx.y, me = blockIdx.x;
    int tid = threadIdx.x;
    __shared__ float sK[8][D_];
    __shared__ float sVW[8][H_ * D_];
    __shared__ float sS[E_][H_ * 8];
    int c = cnt[b * E_ + me];
    const int* lst = mlist + (size_t)(b * E_ + me) * M_;

    if (c >= 1 && c <= 8) {
        for (int k = 0; k < c; ++k) {
            int m = lst[k];
            sK[k][tid] = K[((size_t)b * M_ + m) * D_ + tid];
            const float* Vrow = VW + ((size_t)b * M_ + m) * (H_ * D_);
            for (int e = tid; e < H_ * D_; e += 256) sVW[k][e] = Vrow[e];
        }
        __syncthreads();
        int tot = E_ * H_ * c;
        for (int e = tid; e < tot; e += 256) {
            int q = e / (H_ * c);
            int rem = e % (H_ * c);
            int hh = rem / c, k = rem % c;
            const float* Qrow = Q + ((size_t)b * E_ + q) * D_ + hh * DK_;
            const float* Krow = &sK[k][hh * DK_];
            float dot = 0.f;
            for (int kk = 0; kk < DK_; ++kk) dot += Qrow[kk] * Krow[kk];
            sS[q][hh * 8 + k] = dot * 0.125f;
        }
        __syncthreads();
        {   // softmax over the subset, one (q,h) per thread
            int q = tid >> 2, hh = tid & 3;
            float mx = -1e30f;
            for (int k = 0; k < c; ++k) mx = fmaxf(mx, sS[q][hh * 8 + k]);
            float sm = 0.f;
            for (int k = 0; k < c; ++k) {
                float w = __expf(sS[q][hh * 8 + k] - mx);
                sS[q][hh * 8 + k] = w;
                sm += w;
            }
            float inv = 1.f / sm;
            for (int k = 0; k < c; ++k) sS[q][hh * 8 + k] *= inv;
        }
        __syncthreads();
        for (int q = 0; q < E_; ++q) {
            float acc = 0.f;
            for (int hh = 0; hh < H_; ++hh)
                for (int k = 0; k < c; ++k)
                    acc += sS[q][hh * 8 + k] * sVW[k][hh * D_ + tid];
            int row = transposed ? (q * E_ + me) : (me * E_ + q);
            out[((size_t)b * OUTROWS + baserow + row) * D_ + tid] = acc;
        }
    } else if (c == 0) {
        // fully masked row -> softmax uniform over all M mentions
        float s = 0.f;
        for (int m = 0; m < M_; ++m)
            for (int hh = 0; hh < H_; ++hh)
                s += VW[((size_t)b * M_ + m) * (H_ * D_) + hh * D_ + tid];
        s *= (1.0f / M_);
        for (int q = 0; q < E_; ++q) {
            int row = transposed ? (q * E_ + me) : (me * E_ + q);
            out[((size_t)b * OUTROWS + baserow + row) * D_ + tid] = s;
        }
    } else {
        // general slow path (correctness parachute; not hit with this data)
        __shared__ float shMx[E_][H_], shSm[E_][H_];
        {
            int q = tid >> 2, hh = tid & 3;
            const float* Qrow = Q + ((size_t)b * E_ + q) * D_ + hh * DK_;
            float mx = -1e30f;
            for (int k = 0; k < c; ++k) {
                int m = lst[k];
                const float* Krow = K + ((size_t)b * M_ + m) * D_ + hh * DK_;
                float dot = 0.f;
                for (int kk = 0; kk < DK_; ++kk) dot += Qrow[kk] * Krow[kk];
                mx = fmaxf(mx, dot * 0.125f);
            }
            float sm = 0.f;
            for (int k = 0; k < c; ++k) {
                int m = lst[k];
                const float* Krow = K + ((size_t)b * M_ + m) * D_ + hh * DK_;
                float dot = 0.f;
                for (int kk = 0; kk < DK_; ++kk) dot += Qrow[kk] * Krow[kk];
                sm += __expf(dot * 0.125f - mx);
            }
            shMx[q][hh] = mx;
            shSm[q][hh] = sm;
        }
        __syncthreads();
        for (int q = 0; q < E_; ++q) {
            float acc = 0.f;
            for (int hh = 0; hh < H_; ++hh) {
                float mx = shMx[q][hh], inv = 1.f / shSm[q][hh];
                const float* Qrow = Q + ((size_t)b * E_ + q) * D_ + hh * DK_;
                for (int k = 0; k < c; ++k) {
                    int m = lst[k];
                    const float* Krow = K + ((size_t)b * M_ + m) * D_ + hh * DK_;
                    float dot = 0.f;
                    for (int kk = 0; kk < DK_; ++kk) dot += Qrow[kk] * Krow[kk];
                    float w = __expf(dot * 0.125f - mx) * inv;
                    acc += w * VW[((size_t)b * M_ + m) * (H_ * D_) + hh * D_ + tid];
                }
            }
            int row = transposed ? (q * E_ + me) : (me * E_ + q);
            out[((size_t)b * OUTROWS + baserow + row) * D_ + tid] = acc;
        }
    }
}

extern "C" void kernel_launch(void* const* d_in, const int* in_sizes, int n_in,
                              void* d_out, int out_size, void* d_ws, size_t ws_size,
                              hipStream_t stream) {
    const float* nodes     = (const float*)d_in[0];
    const float* adj       = (const float*)d_in[1];
    const float* mentions  = (const float*)d_in[2];
    const float* sentences = (const float*)d_in[3];
    const float* Wr0 = (const float*)d_in[4];
    const float* br0 = (const float*)d_in[5];
    const float* Wr1 = (const float*)d_in[6];
    const float* br1 = (const float*)d_in[7];
    const float* W00 = (const float*)d_in[8];
    const float* b00 = (const float*)d_in[9];
    const float* W01 = (const float*)d_in[10];
    const float* b01 = (const float*)d_in[11];
    const float* Wq_h = (const float*)d_in[12];
    const float* Wk_h = (const float*)d_in[13];
    const float* Wv_h = (const float*)d_in[14];
    const float* Wo_h = (const float*)d_in[15];
    const float* Wq_t = (const float*)d_in[16];
    const float* Wk_t = (const float*)d_in[17];
    const float* Wv_t = (const float*)d_in[18];
    const float* Wo_t = (const float*)d_in[19];
    const int* info_eid = (const int*)d_in[20];
    const int* info_sid = (const int*)d_in[21];
    float* out  = (float*)d_out;
    float* pool = (float*)d_ws;

    // stage 1 (RGCN) layout
    float* xW  = pool;             // (R,B,N,D) 2,293,760
    float* tb  = pool + 2293760;   // (B,N,D)     458,752
    float* h   = pool + 2752512;   // (B,N,D)     458,752
    float* den = pool + 3211264;   // (B,N)         1,792
    // stage 2 (attention) layout — reuses stage-1 space after it is consumed
    float* ents = pool;            // (B,E,D)     131,072
    float* msr  = pool + 131072;   // (B,M,D)     262,144
    float* Kh   = pool + 393216;
    float* Kt   = pool + 655360;
    float* Vh   = pool + 917504;
    float* Vt   = pool + 1179648;
    float* Qh   = pool + 1441792;
    float* Qt   = pool + 1572864;
    float* VWh  = pool + 1703936;  // (B,M,H,D) 1,048,576
    float* VWt  = pool + 2752512;  // (B,M,H,D) 1,048,576  (end 3,801,088 floats)
    int* cnt   = (int*)(pool + 3801088);
    int* mlist = cnt + B_ * E_;

    dim3 blk(16, 16);

    denoms_kernel<<<B_ * N_, 256, 0, stream>>>(adj, den);
    // xW0 = nodes @ Wr0 + br0  (per r)
    matmul_bias<<<dim3(8, 56, 5), blk, 0, stream>>>(nodes, 0, IN_, Wr0, (long long)IN_ * D_, D_,
                                                    xW, (long long)B_ * N_ * D_, D_, br0, D_,
                                                    B_ * N_, D_, IN_);
    // t0 = nodes @ W00 + b00
    matmul_bias<<<dim3(8, 56, 1), blk, 0, stream>>>(nodes, 0, IN_, W00, 0, D_,
                                                    tb, 0, D_, b00, 0, B_ * N_, D_, IN_);
    axw_epilogue<<<dim3(8, 7, 8), blk, 0, stream>>>(adj, xW, tb, den, h, (long long)N_ * D_);
    // xW1 = h @ Wr1 + br1
    matmul_bias<<<dim3(8, 56, 5), blk, 0, stream>>>(h, 0, D_, Wr1, (long long)D_ * D_, D_,
                                                    xW, (long long)B_ * N_ * D_, D_, br1, D_,
                                                    B_ * N_, D_, D_);
    // t1 = h @ W01 + b01
    matmul_bias<<<dim3(8, 56, 1), blk, 0, stream>>>(h, 0, D_, W01, 0, D_,
                                                    tb, 0, D_, b01, 0, B_ * N_, D_, D_);
    // gcn_out -> first N rows of each batch of out
    axw_epilogue<<<dim3(8, 7, 8), blk, 0, stream>>>(adj, xW, tb, den, out,
                                                    (long long)OUTROWS * D_);
    gather_ents<<<(B_ * E_ * D_ + 255) / 256, 256, 0, stream>>>(out, ents);
    gather_msr<<<(B_ * M_ * D_ + 255) / 256, 256, 0, stream>>>(sentences, info_sid, msr);
    mention_lists<<<2, 256, 0, stream>>>(info_eid, cnt, mlist);

    // projections (no bias in _mha)
    matmul_bias<<<dim3(8, 32, 1), blk, 0, stream>>>(msr, 0, D_, Wk_h, 0, D_, Kh, 0, D_,
                                                    nullptr, 0, B_ * M_, D_, D_);
    matmul_bias<<<dim3(8, 32, 1), blk, 0, stream>>>(msr, 0, D_, Wk_t, 0, D_, Kt, 0, D_,
                                                    nullptr, 0, B_ * M_, D_, D_);
    matmul_bias<<<dim3(8, 32, 1), blk, 0, stream>>>(mentions, 0, D_, Wv_h, 0, D_, Vh, 0, D_,
                                                    nullptr, 0, B_ * M_, D_, D_);
    matmul_bias<<<dim3(8, 32, 1), blk, 0, stream>>>(mentions, 0, D_, Wv_t, 0, D_, Vt, 0, D_,
                                                    nullptr, 0, B_ * M_, D_, D_);
    matmul_bias<<<dim3(8, 16, 1), blk, 0, stream>>>(ents, 0, D_, Wq_h, 0, D_, Qh, 0, D_,
                                                    nullptr, 0, B_ * E_, D_, D_);
    matmul_bias<<<dim3(8, 16, 1), blk, 0, stream>>>(ents, 0, D_, Wq_t, 0, D_, Qt, 0, D_,
                                                    nullptr, 0, B_ * E_, D_, D_);
    // VW[b,m,h,:] = V[b,m,h-block] @ Wo[h-block,:]   (z = h)
    matmul_bias<<<dim3(8, 32, 4), blk, 0, stream>>>(Vh, DK_, D_, Wo_h, (long long)DK_ * D_, D_,
                                                    VWh, D_, H_ * D_, nullptr, 0,
                                                    B_ * M_, D_, DK_);
    matmul_bias<<<dim3(8, 32, 4), blk, 0, stream>>>(Vt, DK_, D_, Wo_t, (long long)DK_ * D_, D_,
                                                    VWt, D_, H_ * D_, nullptr, 0,
                                                    B_ * M_, D_, DK_);

    // rep_h: mask entity = outer index i, query = inner j
    combine_kernel<<<dim3(E_, B_), 256, 0, stream>>>(Qh, Kh, VWh, cnt, mlist, out, N_, 0);
    // rep_t: mask entity = inner index j, query = outer i
    combine_kernel<<<dim3(E_, B_), 256, 0, stream>>>(Qt, Kt, VWt, cnt, mlist, out,
                                                     N_ + E_ * E_, 1);
}

// Round 2
// 396.905 us; speedup vs baseline: 1.4108x; 1.4108x over previous
//
#include <hip/hip_runtime.h>
#include <math.h>

#define B_ 8
#define N_ 224
#define E_ 64
#define M_ 128
#define S_ 32
#define D_ 256
#define IN_ 300
#define R_ 5
#define H_ 4
#define DK_ 64
#define OUTROWS (N_ + 2 * E_ * E_)   // 8416
#define CAP_ 192                     // max edges per (b,n); E[cnt]=56, P(>100)~0

// ---------- build per-(b,n) edge lists + denominators (deterministic) ----------
__global__ __launch_bounds__(256) void build_edges(
    const float* __restrict__ adj, int* __restrict__ ecnt,
    int* __restrict__ elist, float* __restrict__ evals, float* __restrict__ den) {
    int bn = blockIdx.x;
    int b = bn / N_, n = bn % N_;
    int tid = threadIdx.x;
    __shared__ int sc[256];
    __shared__ float sv[256];
    int idxs[5]; float vals[5];
    int cloc = 0; float sloc = 0.f;
    for (int e = tid; e < R_ * N_; e += 256) {
        int r = e / N_, m = e % N_;
        float v = adj[(((size_t)(b * R_ + r)) * N_ + n) * N_ + m];
        if (v != 0.f) { idxs[cloc] = e; vals[cloc] = v; ++cloc; sloc += v; }
    }
    sc[tid] = cloc; sv[tid] = sloc;
    __syncthreads();
    // inclusive scan over counts (deterministic order)
    for (int st = 1; st < 256; st <<= 1) {
        int add = (tid >= st) ? sc[tid - st] : 0;
        __syncthreads();
        sc[tid] += add;
        __syncthreads();
    }
    int off = sc[tid] - cloc;
    int total = sc[255];
    // reduce value sum
    for (int st = 128; st > 0; st >>= 1) {
        if (tid < st) sv[tid] += sv[tid + st];
        __syncthreads();
    }
    size_t base = (size_t)bn * CAP_;
    for (int i = 0; i < cloc; ++i) {
        int p = off + i;
        if (p < CAP_) { elist[base + p] = idxs[i]; evals[base + p] = vals[i]; }
    }
    if (tid == 0) {
        ecnt[bn] = total < CAP_ ? total : CAP_;
        den[bn] = sv[0] + 1.0f;
    }
}

// ---------- AxW via edge gather, fused epilogue: relu((Σ val·xW + t)/den) ----------
__global__ __launch_bounds__(256) void axw_gather(
    const float* __restrict__ xW, const float* __restrict__ t,
    const int* __restrict__ ecnt, const int* __restrict__ elist,
    const float* __restrict__ evals, const float* __restrict__ den,
    float* __restrict__ out, long long out_bstride) {
    int bn = blockIdx.x;
    int b = bn / N_, n = bn % N_;
    int d = threadIdx.x;
    int c = ecnt[bn];
    const int* lst = elist + (size_t)bn * CAP_;
    const float* vls = evals + (size_t)bn * CAP_;
    float acc = 0.f;
#pragma unroll 4
    for (int k = 0; k < c; ++k) {
        int e = lst[k];
        float v = vls[k];
        int r = e / N_, m = e % N_;
        acc += v * xW[(((size_t)r * B_ + b) * N_ + m) * D_ + d];
    }
    float val = (acc + t[(size_t)bn * D_ + d]) / den[bn];
    out[(size_t)b * out_bstride + (size_t)n * D_ + d] = val > 0.f ? val : 0.f;
}

// ---------- 64x64-tile fp32 matmul, 4x4 per thread, z-sliced, optional bias ----------
__global__ __launch_bounds__(256) void matmul64(
    const float* __restrict__ A, long long azs, int lda,
    const float* __restrict__ Bm, long long bzs, int ldb,
    float* __restrict__ C, long long czs, int ldc,
    const float* __restrict__ bias, long long biaszs,
    int Mr, int Nc, int K) {
    A  += (size_t)blockIdx.z * azs;
    Bm += (size_t)blockIdx.z * bzs;
    C  += (size_t)blockIdx.z * czs;
    if (bias) bias += (size_t)blockIdx.z * biaszs;
    __shared__ float As[16][64];
    __shared__ float Bs[16][64];
    int tx = threadIdx.x, ty = threadIdx.y;
    int tid = ty * 16 + tx;
    int row0 = blockIdx.y * 64, col0 = blockIdx.x * 64;
    int am = tid >> 2, aq = tid & 3;    // A stage: row am, K-quad aq
    int bk = tid >> 4, bq = tid & 15;   // B stage: K-row bk, N-quad bq
    float acc[4][4] = {};
    for (int k0 = 0; k0 < K; k0 += 16) {
        // A tile: rows row0+am, cols k0+aq*4..+3  -> As[kk][m]
        {
            float a0 = 0.f, a1 = 0.f, a2 = 0.f, a3 = 0.f;
            int gr = row0 + am, gc = k0 + aq * 4;
            if (gr < Mr) {
                if (gc + 3 < K) {
                    float4 av = *(const float4*)&A[(size_t)gr * lda + gc];
                    a0 = av.x; a1 = av.y; a2 = av.z; a3 = av.w;
                } else {
                    if (gc + 0 < K) a0 = A[(size_t)gr * lda + gc + 0];
                    if (gc + 1 < K) a1 = A[(size_t)gr * lda + gc + 1];
                    if (gc + 2 < K) a2 = A[(size_t)gr * lda + gc + 2];
                    if (gc + 3 < K) a3 = A[(size_t)gr * lda + gc + 3];
                }
            }
            As[aq * 4 + 0][am] = a0;
            As[aq * 4 + 1][am] = a1;
            As[aq * 4 + 2][am] = a2;
            As[aq * 4 + 3][am] = a3;
        }
        // B tile: row k0+bk, cols col0+bq*4..+3 -> Bs[bk][n] (float4 write)
        {
            float4 bv = make_float4(0.f, 0.f, 0.f, 0.f);
            int gk = k0 + bk, gc = col0 + bq * 4;
            if (gk < K) {
                if (gc + 3 < Nc) {
                    bv = *(const float4*)&Bm[(size_t)gk * ldb + gc];
                } else {
                    float* bp = (float*)&bv;
                    for (int j = 0; j < 4; ++j)
                        if (gc + j < Nc) bp[j] = Bm[(size_t)gk * ldb + gc + j];
                }
            }
            *(float4*)&Bs[bk][bq * 4] = bv;
        }
        __syncthreads();
#pragma unroll
        for (int kk = 0; kk < 16; ++kk) {
            float4 a4 = *(const float4*)&As[kk][ty * 4];
            float4 b4 = *(const float4*)&Bs[kk][tx * 4];
            const float* ar = (const float*)&a4;
            const float* br = (const float*)&b4;
#pragma unroll
            for (int i = 0; i < 4; ++i)
#pragma unroll
                for (int j = 0; j < 4; ++j)
                    acc[i][j] += ar[i] * br[j];
        }
        __syncthreads();
    }
#pragma unroll
    for (int i = 0; i < 4; ++i) {
        int gr = row0 + ty * 4 + i;
        if (gr >= Mr) continue;
        int gc = col0 + tx * 4;
        float4 v = make_float4(acc[i][0], acc[i][1], acc[i][2], acc[i][3]);
        if (bias) {
            v.x += bias[gc + 0]; v.y += bias[gc + 1];
            v.z += bias[gc + 2]; v.w += bias[gc + 3];
        }
        if (gc + 3 < Nc) {
            *(float4*)&C[(size_t)gr * ldc + gc] = v;
        } else {
            const float* vp = (const float*)&v;
            for (int j = 0; j < 4; ++j)
                if (gc + j < Nc) C[(size_t)gr * ldc + gc + j] = vp[j];
        }
    }
}

// ---------------- small gathers ----------------
__global__ void gather_msr(const float* __restrict__ sentences, const int* __restrict__ sid,
                           float* __restrict__ msr) {
    int idx = blockIdx.x * 256 + threadIdx.x;
    if (idx >= B_ * M_ * D_) return;
    int bm = idx / D_, d = idx % D_;
    msr[idx] = sentences[(size_t)sid[bm] * D_ + d];
}
__global__ void mention_lists(const int* __restrict__ eid, int* __restrict__ cnt,
                              int* __restrict__ mlist) {
    int t = blockIdx.x * blockDim.x + threadIdx.x;
    if (t >= B_ * E_) return;
    int b = t / E_, i = t % E_;
    int c = 0;
    for (int m = 0; m < M_; ++m)
        if (eid[b * M_ + m] == i) mlist[(size_t)t * M_ + c++] = m;
    cnt[t] = c;
}

// ------------- per (b, masked-entity) attention combine -------------
__global__ __launch_bounds__(256) void combine_kernel(
    const float* __restrict__ Q, const float* __restrict__ K,
    const float* __restrict__ VW, const int* __restrict__ cnt,
    const int* __restrict__ mlist, float* __restrict__ out,
    int baserow, int transposed) {
    int b = blockIdx.y, me = blockIdx.x;
    int tid = threadIdx.x;
    __shared__ float sK[8][D_];
    __shared__ float sVW[8][H_ * D_];
    __shared__ float sS[E_][H_ * 8];
    int c = cnt[b * E_ + me];
    const int* lst = mlist + (size_t)(b * E_ + me) * M_;

    if (c >= 1 && c <= 8) {
        for (int k = 0; k < c; ++k) {
            int m = lst[k];
            sK[k][tid] = K[((size_t)b * M_ + m) * D_ + tid];
            const float* Vrow = VW + ((size_t)b * M_ + m) * (H_ * D_);
            for (int e = tid; e < H_ * D_; e += 256) sVW[k][e] = Vrow[e];
        }
        __syncthreads();
        int tot = E_ * H_ * c;
        for (int e = tid; e < tot; e += 256) {
            int q = e / (H_ * c);
            int rem = e % (H_ * c);
            int hh = rem / c, k = rem % c;
            const float* Qrow = Q + ((size_t)b * E_ + q) * D_ + hh * DK_;
            const float* Krow = &sK[k][hh * DK_];
            float dot = 0.f;
            for (int kk = 0; kk < DK_; ++kk) dot += Qrow[kk] * Krow[kk];
            sS[q][hh * 8 + k] = dot * 0.125f;
        }
        __syncthreads();
        {   // softmax over the subset, one (q,h) per thread
            int q = tid >> 2, hh = tid & 3;
            float mx = -1e30f;
            for (int k = 0; k < c; ++k) mx = fmaxf(mx, sS[q][hh * 8 + k]);
            float sm = 0.f;
            for (int k = 0; k < c; ++k) {
                float w = __expf(sS[q][hh * 8 + k] - mx);
                sS[q][hh * 8 + k] = w;
                sm += w;
            }
            float inv = 1.f / sm;
            for (int k = 0; k < c; ++k) sS[q][hh * 8 + k] *= inv;
        }
        __syncthreads();
        for (int q = 0; q < E_; ++q) {
            float acc = 0.f;
            for (int hh = 0; hh < H_; ++hh)
                for (int k = 0; k < c; ++k)
                    acc += sS[q][hh * 8 + k] * sVW[k][hh * D_ + tid];
            int row = transposed ? (q * E_ + me) : (me * E_ + q);
            out[((size_t)b * OUTROWS + baserow + row) * D_ + tid] = acc;
        }
    } else if (c == 0) {
        float s = 0.f;
        for (int m = 0; m < M_; ++m)
            for (int hh = 0; hh < H_; ++hh)
                s += VW[((size_t)b * M_ + m) * (H_ * D_) + hh * D_ + tid];
        s *= (1.0f / M_);
        for (int q = 0; q < E_; ++q) {
            int row = transposed ? (q * E_ + me) : (me * E_ + q);
            out[((size_t)b * OUTROWS + baserow + row) * D_ + tid] = s;
        }
    } else {
        __shared__ float shMx[E_][H_], shSm[E_][H_];
        {
            int q = tid >> 2, hh = tid & 3;
            const float* Qrow = Q + ((size_t)b * E_ + q) * D_ + hh * DK_;
            float mx = -1e30f;
            for (int k = 0; k < c; ++k) {
                int m = lst[k];
                const float* Krow = K + ((size_t)b * M_ + m) * D_ + hh * DK_;
                float dot = 0.f;
                for (int kk = 0; kk < DK_; ++kk) dot += Qrow[kk] * Krow[kk];
                mx = fmaxf(mx, dot * 0.125f);
            }
            float sm = 0.f;
            for (int k = 0; k < c; ++k) {
                int m = lst[k];
                const float* Krow = K + ((size_t)b * M_ + m) * D_ + hh * DK_;
                float dot = 0.f;
                for (int kk = 0; kk < DK_; ++kk) dot += Qrow[kk] * Krow[kk];
                sm += __expf(dot * 0.125f - mx);
            }
            shMx[q][hh] = mx;
            shSm[q][hh] = sm;
        }
        __syncthreads();
        for (int q = 0; q < E_; ++q) {
            float acc = 0.f;
            for (int hh = 0; hh < H_; ++hh) {
                float mx = shMx[q][hh], inv = 1.f / shSm[q][hh];
                const float* Qrow = Q + ((size_t)b * E_ + q) * D_ + hh * DK_;
                for (int k = 0; k < c; ++k) {
                    int m = lst[k];
                    const float* Krow = K + ((size_t)b * M_ + m) * D_ + hh * DK_;
                    float dot = 0.f;
                    for (int kk = 0; kk < DK_; ++kk) dot += Qrow[kk] * Krow[kk];
                    float w = __expf(dot * 0.125f - mx) * inv;
                    acc += w * VW[((size_t)b * M_ + m) * (H_ * D_) + hh * D_ + tid];
                }
            }
            int row = transposed ? (q * E_ + me) : (me * E_ + q);
            out[((size_t)b * OUTROWS + baserow + row) * D_ + tid] = acc;
        }
    }
}

extern "C" void kernel_launch(void* const* d_in, const int* in_sizes, int n_in,
                              void* d_out, int out_size, void* d_ws, size_t ws_size,
                              hipStream_t stream) {
    const float* nodes     = (const float*)d_in[0];
    const float* adj       = (const float*)d_in[1];
    const float* mentions  = (const float*)d_in[2];
    const float* sentences = (const float*)d_in[3];
    const float* Wr0 = (const float*)d_in[4];
    const float* br0 = (const float*)d_in[5];
    const float* Wr1 = (const float*)d_in[6];
    const float* br1 = (const float*)d_in[7];
    const float* W00 = (const float*)d_in[8];
    const float* b00 = (const float*)d_in[9];
    const float* W01 = (const float*)d_in[10];
    const float* b01 = (const float*)d_in[11];
    const float* Wq_h = (const float*)d_in[12];
    const float* Wk_h = (const float*)d_in[13];
    const float* Wv_h = (const float*)d_in[14];
    const float* Wo_h = (const float*)d_in[15];
    const float* Wq_t = (const float*)d_in[16];
    const float* Wk_t = (const float*)d_in[17];
    const float* Wv_t = (const float*)d_in[18];
    const float* Wo_t = (const float*)d_in[19];
    const int* info_eid = (const int*)d_in[20];
    const int* info_sid = (const int*)d_in[21];
    float* out  = (float*)d_out;
    float* pool = (float*)d_ws;

    // ---- stage 1 layout (floats) ----
    float* xW  = pool;               // (R,B,N,D) 2,293,760
    float* tb  = pool + 2293760;     // (B,N,D)     458,752
    float* h   = pool + 2752512;     // (B,N,D)     458,752
    float* den = pool + 3211264;     // (B,N)         1,792
    int*   elist = (int*)(pool + 3213056);   // B*N*CAP = 344,064 ints
    float* evals = pool + 3557120;           // 344,064 floats
    int*   ecnt  = (int*)(pool + 3901184);   // 1,792
    int*   mcnt  = (int*)(pool + 3902976);   // 512
    int*   mlist = (int*)(pool + 3903488);   // 65,536
    // ---- stage 2 layout (reuses stage-1 space once consumed) ----
    float* msr = pool;               // (B,M,D)   262,144
    float* Kh  = pool + 262144;
    float* Kt  = pool + 524288;
    float* Vh  = pool + 786432;
    float* Vt  = pool + 1048576;
    float* Qh  = pool + 1310720;     // (B,E,D)   131,072
    float* Qt  = pool + 1441792;
    float* VWh = pool + 1572864;     // (B,M,H,D) 1,048,576
    float* VWt = pool + 2621440;     // ends 3,670,016

    dim3 blk(16, 16);

    // edges + denoms (single 8 MB pass over adj)
    build_edges<<<B_ * N_, 256, 0, stream>>>(adj, ecnt, elist, evals, den);
    // xW0 = nodes @ Wr0 + br0 (per r)
    matmul64<<<dim3(4, 28, 5), blk, 0, stream>>>(nodes, 0, IN_, Wr0, (long long)IN_ * D_, D_,
                                                 xW, (long long)B_ * N_ * D_, D_, br0, D_,
                                                 B_ * N_, D_, IN_);
    // t0 = nodes @ W00 + b00
    matmul64<<<dim3(4, 28, 1), blk, 0, stream>>>(nodes, 0, IN_, W00, 0, D_,
                                                 tb, 0, D_, b00, 0, B_ * N_, D_, IN_);
    axw_gather<<<B_ * N_, 256, 0, stream>>>(xW, tb, ecnt, elist, evals, den, h,
                                            (long long)N_ * D_);
    // xW1 = h @ Wr1 + br1
    matmul64<<<dim3(4, 28, 5), blk, 0, stream>>>(h, 0, D_, Wr1, (long long)D_ * D_, D_,
                                                 xW, (long long)B_ * N_ * D_, D_, br1, D_,
                                                 B_ * N_, D_, D_);
    // t1 = h @ W01 + b01
    matmul64<<<dim3(4, 28, 1), blk, 0, stream>>>(h, 0, D_, W01, 0, D_,
                                                 tb, 0, D_, b01, 0, B_ * N_, D_, D_);
    // gcn_out -> first N rows of each batch of out
    axw_gather<<<B_ * N_, 256, 0, stream>>>(xW, tb, ecnt, elist, evals, den, out,
                                            (long long)OUTROWS * D_);

    gather_msr<<<(B_ * M_ * D_ + 255) / 256, 256, 0, stream>>>(sentences, info_sid, msr);
    mention_lists<<<2, 256, 0, stream>>>(info_eid, mcnt, mlist);

    // projections (no bias in _mha)
    matmul64<<<dim3(4, 16, 1), blk, 0, stream>>>(msr, 0, D_, Wk_h, 0, D_, Kh, 0, D_,
                                                 nullptr, 0, B_ * M_, D_, D_);
    matmul64<<<dim3(4, 16, 1), blk, 0, stream>>>(msr, 0, D_, Wk_t, 0, D_, Kt, 0, D_,
                                                 nullptr, 0, B_ * M_, D_, D_);
    matmul64<<<dim3(4, 16, 1), blk, 0, stream>>>(mentions, 0, D_, Wv_h, 0, D_, Vh, 0, D_,
                                                 nullptr, 0, B_ * M_, D_, D_);
    matmul64<<<dim3(4, 16, 1), blk, 0, stream>>>(mentions, 0, D_, Wv_t, 0, D_, Vt, 0, D_,
                                                 nullptr, 0, B_ * M_, D_, D_);
    // Q projections batched directly over `out` rows (ents = first E rows per batch)
    matmul64<<<dim3(4, 1, 8), blk, 0, stream>>>(out, (long long)OUTROWS * D_, D_,
                                                Wq_h, 0, D_, Qh, (long long)E_ * D_, D_,
                                                nullptr, 0, E_, D_, D_);
    matmul64<<<dim3(4, 1, 8), blk, 0, stream>>>(out, (long long)OUTROWS * D_, D_,
                                                Wq_t, 0, D_, Qt, (long long)E_ * D_, D_,
                                                nullptr, 0, E_, D_, D_);
    // VW[b,m,h,:] = V[b,m,h-block] @ Wo[h-block,:]   (z = h)
    matmul64<<<dim3(4, 16, 4), blk, 0, stream>>>(Vh, DK_, D_, Wo_h, (long long)DK_ * D_, D_,
                                                 VWh, D_, H_ * D_, nullptr, 0,
                                                 B_ * M_, D_, DK_);
    matmul64<<<dim3(4, 16, 4), blk, 0, stream>>>(Vt, DK_, D_, Wo_t, (long long)DK_ * D_, D_,
                                                 VWt, D_, H_ * D_, nullptr, 0,
                                                 B_ * M_, D_, DK_);

    // rep_h: mask entity = outer index i, query = inner j
    combine_kernel<<<dim3(E_, B_), 256, 0, stream>>>(Qh, Kh, VWh, mcnt, mlist, out, N_, 0);
    // rep_t: mask entity = inner index j, query = outer i
    combine_kernel<<<dim3(E_, B_), 256, 0, stream>>>(Qt, Kt, VWt, mcnt, mlist, out,
                                                     N_ + E_ * E_, 1);
}

// Round 3
// 278.134 us; speedup vs baseline: 2.0132x; 1.4270x over previous
//
#include <hip/hip_runtime.h>
#include <math.h>

#define B_ 8
#define N_ 224
#define E_ 64
#define M_ 128
#define S_ 32
#define D_ 256
#define IN_ 300
#define R_ 5
#define H_ 4
#define DK_ 64
#define OUTROWS (N_ + 2 * E_ * E_)   // 8416
#define CAP_ 192

typedef __attribute__((ext_vector_type(8))) short bf16x8;
typedef __attribute__((ext_vector_type(4))) float f32x4;

__device__ inline short f2bf(float f) {
    union { float f; unsigned u; } x; x.f = f;
    unsigned u = x.u;
    unsigned r = (u + 0x7fffu + ((u >> 16) & 1u)) >> 16;
    return (short)r;
}

// ---------------- pack all weights into one contiguous ws block ----------------
// layout (floats): [Wr0(384000) W00(76800)] [br0(1280) b00(256)]
//                  [Wr1(327680) W01(65536)] [br1(1280) b01(256)]
//                  [Wk_h Wk_t] [Wv_h Wv_t] [Wq_h Wq_t] [Wo_h Wo_t]  (65536 each)
#define WTOT 1381376
__global__ void pack_weights(float* __restrict__ W,
    const float* Wr0, const float* W00, const float* br0, const float* b00,
    const float* Wr1, const float* W01, const float* br1, const float* b01,
    const float* Wkh, const float* Wkt, const float* Wvh, const float* Wvt,
    const float* Wqh, const float* Wqt, const float* Woh, const float* Wot) {
    for (int i = blockIdx.x * 256 + threadIdx.x; i < WTOT; i += gridDim.x * 256) {
        float v; int j = i;
        if (j < 384000) v = Wr0[j];
        else if ((j -= 384000) < 76800) v = W00[j];
        else if ((j -= 76800) < 1280) v = br0[j];
        else if ((j -= 1280) < 256) v = b00[j];
        else if ((j -= 256) < 327680) v = Wr1[j];
        else if ((j -= 327680) < 65536) v = W01[j];
        else if ((j -= 65536) < 1280) v = br1[j];
        else if ((j -= 1280) < 256) v = b01[j];
        else if ((j -= 256) < 65536) v = Wkh[j];
        else if ((j -= 65536) < 65536) v = Wkt[j];
        else if ((j -= 65536) < 65536) v = Wvh[j];
        else if ((j -= 65536) < 65536) v = Wvt[j];
        else if ((j -= 65536) < 65536) v = Wqh[j];
        else if ((j -= 65536) < 65536) v = Wqt[j];
        else if ((j -= 65536) < 65536) v = Woh[j];
        else { j -= 65536; v = Wot[j]; }
        W[i] = v;
    }
}

// ---------- build per-(b,n) edge lists + denominators (deterministic) ----------
__global__ __launch_bounds__(256) void build_edges(
    const float* __restrict__ adj, int* __restrict__ ecnt,
    int* __restrict__ elist, float* __restrict__ evals, float* __restrict__ den) {
    int bn = blockIdx.x;
    int b = bn / N_, n = bn % N_;
    int tid = threadIdx.x;
    __shared__ int sc[256];
    __shared__ float sv[256];
    int idxs[5]; float vals[5];
    int cloc = 0; float sloc = 0.f;
    for (int e = tid; e < R_ * N_; e += 256) {
        int r = e / N_, m = e % N_;
        float v = adj[(((size_t)(b * R_ + r)) * N_ + n) * N_ + m];
        if (v != 0.f) { idxs[cloc] = e; vals[cloc] = v; ++cloc; sloc += v; }
    }
    sc[tid] = cloc; sv[tid] = sloc;
    __syncthreads();
    for (int st = 1; st < 256; st <<= 1) {
        int add = (tid >= st) ? sc[tid - st] : 0;
        __syncthreads();
        sc[tid] += add;
        __syncthreads();
    }
    int off = sc[tid] - cloc;
    int total = sc[255];
    for (int st = 128; st > 0; st >>= 1) {
        if (tid < st) sv[tid] += sv[tid + st];
        __syncthreads();
    }
    size_t base = (size_t)bn * CAP_;
    for (int i = 0; i < cloc; ++i) {
        int p = off + i;
        if (p < CAP_) { elist[base + p] = idxs[i]; evals[base + p] = vals[i]; }
    }
    if (tid == 0) {
        ecnt[bn] = total < CAP_ ? total : CAP_;
        den[bn] = sv[0] + 1.0f;
    }
}

// ---------- AxW via edge gather, fused epilogue: relu((Σ val·xW + t)/den) ----------
__global__ __launch_bounds__(256) void axw_gather(
    const float* __restrict__ xW, const float* __restrict__ t,
    const int* __restrict__ ecnt, const int* __restrict__ elist,
    const float* __restrict__ evals, const float* __restrict__ den,
    float* __restrict__ out, long long out_bstride) {
    int bn = blockIdx.x;
    int b = bn / N_, n = bn % N_;
    int d = threadIdx.x;
    int c = ecnt[bn];
    const int* lst = elist + (size_t)bn * CAP_;
    const float* vls = evals + (size_t)bn * CAP_;
    float acc = 0.f;
#pragma unroll 4
    for (int k = 0; k < c; ++k) {
        int e = lst[k];
        float v = vls[k];
        int r = e / N_, m = e % N_;
        acc += v * xW[(((size_t)r * B_ + b) * N_ + m) * D_ + d];
    }
    float val = (acc + t[(size_t)bn * D_ + d]) / den[bn];
    out[(size_t)b * out_bstride + (size_t)n * D_ + d] = val > 0.f ? val : 0.f;
}

// ---------- bf16 MFMA GEMM: C = A@B (+bias), dual-stride z batching ----------
// block 256 threads = 4 waves, tile 64x64, BK=32. z1 = z/ZD, z2 = z%ZD.
// Requires M % 64 == 0, N % 64 == 0 (true for all call sites).
__global__ __launch_bounds__(256) void gemm_bf16(
    const float* __restrict__ A, long long azs1, long long azs2, int lda,
    const float* __restrict__ Bm, long long bzs1, long long bzs2, int ldb,
    float* __restrict__ C, long long czs1, long long czs2, int ldc,
    const float* __restrict__ bias, long long biaszs,
    int Mr, int Nc, int K, int ZD) {
    int z = blockIdx.z;
    int z1 = z / ZD, z2 = z % ZD;
    A  += (size_t)z1 * azs1 + (size_t)z2 * azs2;
    Bm += (size_t)z1 * bzs1 + (size_t)z2 * bzs2;
    C  += (size_t)z1 * czs1 + (size_t)z2 * czs2;
    if (bias) bias += (size_t)z1 * biaszs;

    __shared__ short As[64][40];   // [row][k], 80B rows (16B aligned)
    __shared__ short Bs[64][40];   // [col][k] (transposed)
    int tid = threadIdx.x;
    int lane = tid & 63, wv = tid >> 6;
    int wr = wv >> 1, wc = wv & 1;
    int fr = lane & 15, fk = (lane >> 4) * 8;
    int row0 = blockIdx.y * 64, col0 = blockIdx.x * 64;
    int ar = tid >> 2, aq = (tid & 3) * 8;   // A stage
    int bc = tid >> 2, bkq = (tid & 3) * 8;  // B stage

    f32x4 acc00 = {0.f,0.f,0.f,0.f}, acc01 = acc00, acc10 = acc00, acc11 = acc00;

    for (int k0 = 0; k0 < K; k0 += 32) {
        bf16x8 av;
        if (k0 + aq + 8 <= K) {
            const float* ap = &A[(size_t)(row0 + ar) * lda + k0 + aq];
            float4 f1 = *(const float4*)ap;
            float4 f2 = *(const float4*)(ap + 4);
            av[0]=f2bf(f1.x); av[1]=f2bf(f1.y); av[2]=f2bf(f1.z); av[3]=f2bf(f1.w);
            av[4]=f2bf(f2.x); av[5]=f2bf(f2.y); av[6]=f2bf(f2.z); av[7]=f2bf(f2.w);
        } else {
#pragma unroll
            for (int j = 0; j < 8; ++j) {
                int gk = k0 + aq + j;
                av[j] = (gk < K) ? f2bf(A[(size_t)(row0 + ar) * lda + gk]) : (short)0;
            }
        }
        *(bf16x8*)&As[ar][aq] = av;

        bf16x8 bv;
#pragma unroll
        for (int j = 0; j < 8; ++j) {
            int gk = k0 + bkq + j;
            bv[j] = (gk < K) ? f2bf(Bm[(size_t)gk * ldb + col0 + bc]) : (short)0;
        }
        *(bf16x8*)&Bs[bc][bkq] = bv;
        __syncthreads();

        bf16x8 a0 = *(bf16x8*)&As[wr * 32 + fr][fk];
        bf16x8 a1 = *(bf16x8*)&As[wr * 32 + 16 + fr][fk];
        bf16x8 b0 = *(bf16x8*)&Bs[wc * 32 + fr][fk];
        bf16x8 b1 = *(bf16x8*)&Bs[wc * 32 + 16 + fr][fk];
        acc00 = __builtin_amdgcn_mfma_f32_16x16x32_bf16(a0, b0, acc00, 0, 0, 0);
        acc01 = __builtin_amdgcn_mfma_f32_16x16x32_bf16(a0, b1, acc01, 0, 0, 0);
        acc10 = __builtin_amdgcn_mfma_f32_16x16x32_bf16(a1, b0, acc10, 0, 0, 0);
        acc11 = __builtin_amdgcn_mfma_f32_16x16x32_bf16(a1, b1, acc11, 0, 0, 0);
        __syncthreads();
    }

    // epilogue: D row = (lane>>4)*4 + reg, col = lane&15
    int rbase = row0 + wr * 32 + (lane >> 4) * 4;
    int cbase = col0 + wc * 32 + fr;
    f32x4 accs[2][2] = {{acc00, acc01}, {acc10, acc11}};
#pragma unroll
    for (int mi = 0; mi < 2; ++mi) {
#pragma unroll
        for (int nj = 0; nj < 2; ++nj) {
            int cc = cbase + nj * 16;
            float bval = bias ? bias[cc] : 0.f;
#pragma unroll
            for (int r = 0; r < 4; ++r) {
                int cr = rbase + mi * 16 + r;
                C[(size_t)cr * ldc + cc] = accs[mi][nj][r] + bval;
            }
        }
    }
}

// ---------------- fused gathers: ents (from out) + msr (from sentences) ----------------
__global__ void gather_em(const float* __restrict__ outbuf, const float* __restrict__ sentences,
                          const int* __restrict__ sid, float* __restrict__ ents,
                          float* __restrict__ msr) {
    int idx = blockIdx.x * 256 + threadIdx.x;
    if (idx < B_ * E_ * D_) {
        int b = idx / (E_ * D_);
        ents[idx] = outbuf[(size_t)b * OUTROWS * D_ + idx % (E_ * D_)];
    } else {
        int j = idx - B_ * E_ * D_;
        if (j < B_ * M_ * D_) {
            int bm = j / D_, d = j % D_;
            msr[j] = sentences[(size_t)sid[bm] * D_ + d];
        }
    }
}
__global__ void mention_lists(const int* __restrict__ eid, int* __restrict__ cnt,
                              int* __restrict__ mlist) {
    int t = blockIdx.x * blockDim.x + threadIdx.x;
    if (t >= B_ * E_) return;
    int b = t / E_, i = t % E_;
    int c = 0;
    for (int m = 0; m < M_; ++m)
        if (eid[b * M_ + m] == i) mlist[(size_t)t * M_ + c++] = m;
    cnt[t] = c;
}

// ------------- per (b, masked-entity, q-group, rep) attention combine -------------
// grid (E_, B_*4, 2). z=0: rep_h (me = outer i, q = inner j, row = me*E+q)
//                     z=1: rep_t (me = inner j, q = outer i, row = q*E+me)
__global__ __launch_bounds__(256) void combine_kernel(
    const float* __restrict__ Qb, const float* __restrict__ Kb,
    const float* __restrict__ VWb, const int* __restrict__ cnt,
    const int* __restrict__ mlist, float* __restrict__ out) {
    int z = blockIdx.z;
    const float* Q  = Qb  + (size_t)z * (B_ * E_ * D_);
    const float* K  = Kb  + (size_t)z * (B_ * M_ * D_);
    const float* VW = VWb + (size_t)z * (B_ * M_ * H_ * D_);
    int baserow = N_ + z * (E_ * E_);
    int me = blockIdx.x;
    int b = blockIdx.y >> 2, qg = blockIdx.y & 3;
    int qbase = qg * 16;
    int tid = threadIdx.x;
    __shared__ float sBig[8 * H_ * D_];        // fast: sVW[8][1024]; general: P[16][4][128]; c==0: mean[256]
    __shared__ float sS[16][H_][8];
    int c = cnt[b * E_ + me];
    const int* lst = mlist + (size_t)(b * E_ + me) * M_;
    int dq = tid & 63;

    if (c >= 1 && c <= 8) {
        for (int k = 0; k < c; ++k) {
            const float4* Vrow = (const float4*)(VW + ((size_t)b * M_ + lst[k]) * (H_ * D_));
            ((float4*)&sBig[k * (H_ * D_)])[tid] = Vrow[tid];
        }
        int tot = 16 * H_ * c;
        for (int e = tid; e < tot; e += 256) {
            int ql = e / (H_ * c);
            int rem = e % (H_ * c);
            int hh = rem / c, k = rem % c;
            const float* Qrow = Q + ((size_t)b * E_ + qbase + ql) * D_ + hh * DK_;
            const float* Krow = K + ((size_t)b * M_ + lst[k]) * D_ + hh * DK_;
            float dot = 0.f;
#pragma unroll 8
            for (int kk = 0; kk < DK_; ++kk) dot += Qrow[kk] * Krow[kk];
            sS[ql][hh][k] = dot * 0.125f;
        }
        __syncthreads();
        if (tid < 64) {
            int ql = tid >> 2, hh = tid & 3;
            float mx = -1e30f;
            for (int k = 0; k < c; ++k) mx = fmaxf(mx, sS[ql][hh][k]);
            float sm = 0.f;
            for (int k = 0; k < c; ++k) {
                float w = __expf(sS[ql][hh][k] - mx);
                sS[ql][hh][k] = w;
                sm += w;
            }
            float inv = 1.f / sm;
            for (int k = 0; k < c; ++k) sS[ql][hh][k] *= inv;
        }
        __syncthreads();
        for (int qq = tid >> 6; qq < 16; qq += 4) {
            float4 acc = make_float4(0.f, 0.f, 0.f, 0.f);
            for (int hh = 0; hh < H_; ++hh)
                for (int k = 0; k < c; ++k) {
                    float w = sS[qq][hh][k];
                    float4 v = *(const float4*)&sBig[k * (H_ * D_) + hh * D_ + dq * 4];
                    acc.x += w * v.x; acc.y += w * v.y; acc.z += w * v.z; acc.w += w * v.w;
                }
            int q = qbase + qq;
            int row = z ? (q * E_ + me) : (me * E_ + q);
            *(float4*)&out[((size_t)b * OUTROWS + baserow + row) * D_ + dq * 4] = acc;
        }
    } else if (c == 0) {
        // fully masked -> uniform softmax over all M mentions
        float s = 0.f;
        for (int m = 0; m < M_; ++m)
            for (int hh = 0; hh < H_; ++hh)
                s += VW[((size_t)b * M_ + m) * (H_ * D_) + hh * D_ + tid];
        sBig[tid] = s * (1.0f / M_);
        __syncthreads();
        for (int qq = tid >> 6; qq < 16; qq += 4) {
            float4 v = *(const float4*)&sBig[dq * 4];
            int q = qbase + qq;
            int row = z ? (q * E_ + me) : (me * E_ + q);
            *(float4*)&out[((size_t)b * OUTROWS + baserow + row) * D_ + dq * 4] = v;
        }
    } else {
        // general path: scores for 16q x H x c (c <= M=128) in sBig[16][4][128]
        int tot = 16 * H_ * c;
        for (int e = tid; e < tot; e += 256) {
            int ql = e / (H_ * c);
            int rem = e % (H_ * c);
            int hh = rem / c, k = rem % c;
            const float* Qrow = Q + ((size_t)b * E_ + qbase + ql) * D_ + hh * DK_;
            const float* Krow = K + ((size_t)b * M_ + lst[k]) * D_ + hh * DK_;
            float dot = 0.f;
            for (int kk = 0; kk < DK_; ++kk) dot += Qrow[kk] * Krow[kk];
            sBig[(ql * H_ + hh) * M_ + k] = dot * 0.125f;
        }
        __syncthreads();
        if (tid < 64) {
            int ql = tid >> 2, hh = tid & 3;
            float* p = &sBig[(ql * H_ + hh) * M_];
            float mx = -1e30f;
            for (int k = 0; k < c; ++k) mx = fmaxf(mx, p[k]);
            float sm = 0.f;
            for (int k = 0; k < c; ++k) { float w = __expf(p[k] - mx); p[k] = w; sm += w; }
            float inv = 1.f / sm;
            for (int k = 0; k < c; ++k) p[k] *= inv;
        }
        __syncthreads();
        for (int qq = tid >> 6; qq < 16; qq += 4) {
            float4 acc = make_float4(0.f, 0.f, 0.f, 0.f);
            for (int hh = 0; hh < H_; ++hh)
                for (int k = 0; k < c; ++k) {
                    float w = sBig[(qq * H_ + hh) * M_ + k];
                    const float4 v = *(const float4*)&VW[((size_t)b * M_ + lst[k]) * (H_ * D_) + hh * D_ + dq * 4];
                    acc.x += w * v.x; acc.y += w * v.y; acc.z += w * v.z; acc.w += w * v.w;
                }
            int q = qbase + qq;
            int row = z ? (q * E_ + me) : (me * E_ + q);
            *(float4*)&out[((size_t)b * OUTROWS + baserow + row) * D_ + dq * 4] = acc;
        }
    }
}

extern "C" void kernel_launch(void* const* d_in, const int* in_sizes, int n_in,
                              void* d_out, int out_size, void* d_ws, size_t ws_size,
                              hipStream_t stream) {
    const float* nodes     = (const float*)d_in[0];
    const float* adj       = (const float*)d_in[1];
    const float* mentions  = (const float*)d_in[2];
    const float* sentences = (const float*)d_in[3];
    const float* Wr0 = (const float*)d_in[4];
    const float* br0 = (const float*)d_in[5];
    const float* Wr1 = (const float*)d_in[6];
    const float* br1 = (const float*)d_in[7];
    const float* W00 = (const float*)d_in[8];
    const float* b00 = (const float*)d_in[9];
    const float* W01 = (const float*)d_in[10];
    const float* b01 = (const float*)d_in[11];
    const float* Wq_h = (const float*)d_in[12];
    const float* Wk_h = (const float*)d_in[13];
    const float* Wv_h = (const float*)d_in[14];
    const float* Wo_h = (const float*)d_in[15];
    const float* Wq_t = (const float*)d_in[16];
    const float* Wk_t = (const float*)d_in[17];
    const float* Wv_t = (const float*)d_in[18];
    const float* Wo_t = (const float*)d_in[19];
    const int* info_eid = (const int*)d_in[20];
    const int* info_sid = (const int*)d_in[21];
    float* out  = (float*)d_out;
    float* pool = (float*)d_ws;

    // ---- stage 1 region (floats, offset 0) ----
    float* xW  = pool;                       // (R,B,N,D) 2,293,760 ; tb follows contiguously (z=5)
    float* tb  = pool + 2293760;             // (B,N,D)     458,752
    float* h   = pool + 2752512;             // (B,N,D)     458,752
    float* den = pool + 3211264;             // 1,792
    int*   elist = (int*)(pool + 3213056);   // 344,064
    float* evals = pool + 3557120;           // 344,064
    int*   ecnt  = (int*)(pool + 3901184);   // 1,792 -> stage1 ends 3,902,976
    // ---- stage 2 region (overlays stage 1 from offset 0) ----
    float* ents = pool;                      // (B,E,D)       131,072
    float* msr  = pool + 131072;             // (B,M,D)       262,144
    float* KV   = pool + 393216;             // [Kh,Kt,Vh,Vt] 1,048,576
    float* Q2   = pool + 1441792;            // [Qh,Qt]         262,144
    float* VW2  = pool + 1703936;            // [VWh,VWt]     2,097,152 -> ends 3,801,088
    // ---- persistent region ----
    float* W     = pool + 3903488;           // packed weights 1,381,376 -> ends 5,284,864
    int*   mcnt  = (int*)(pool + 5284864);   // 512
    int*   mlist = (int*)(pool + 5285376);   // 65,536 -> total 5,350,912 floats (~21.4 MB)

    // packed-weight sub-offsets
    float* W1cat = W;                 // 6 x 76,800
    float* b1cat = W + 460800;        // 6 x 256
    float* W2cat = W + 462336;        // 6 x 65,536
    float* b2cat = W + 855552;        // 6 x 256
    float* WKcat = W + 857088;        // 2 x 65,536
    float* WVcat = W + 988160;
    float* WQcat = W + 1119232;
    float* WOcat = W + 1250304;

    pack_weights<<<2048, 256, 0, stream>>>(W, Wr0, W00, br0, b00, Wr1, W01, br1, b01,
                                           Wk_h, Wk_t, Wv_h, Wv_t, Wq_h, Wq_t, Wo_h, Wo_t);
    build_edges<<<B_ * N_, 256, 0, stream>>>(adj, ecnt, elist, evals, den);
    mention_lists<<<2, 256, 0, stream>>>(info_eid, mcnt, mlist);

    // L1: z=0..4 -> xW slices, z=5 -> tb (W00 path). C strides contiguous.
    gemm_bf16<<<dim3(4, 28, 6), 256, 0, stream>>>(
        nodes, 0, 0, IN_, W1cat, (long long)IN_ * D_, 0, D_,
        xW, (long long)B_ * N_ * D_, 0, D_, b1cat, D_, B_ * N_, D_, IN_, 1);
    axw_gather<<<B_ * N_, 256, 0, stream>>>(xW, tb, ecnt, elist, evals, den, h,
                                            (long long)N_ * D_);
    // L2
    gemm_bf16<<<dim3(4, 28, 6), 256, 0, stream>>>(
        h, 0, 0, D_, W2cat, (long long)D_ * D_, 0, D_,
        xW, (long long)B_ * N_ * D_, 0, D_, b2cat, D_, B_ * N_, D_, D_, 1);
    axw_gather<<<B_ * N_, 256, 0, stream>>>(xW, tb, ecnt, elist, evals, den, out,
                                            (long long)OUTROWS * D_);

    gather_em<<<(B_ * E_ * D_ + B_ * M_ * D_ + 255) / 256, 256, 0, stream>>>(
        out, sentences, info_sid, ents, msr);

    // K projections: z in {h,t}
    gemm_bf16<<<dim3(4, 16, 2), 256, 0, stream>>>(
        msr, 0, 0, D_, WKcat, (long long)D_ * D_, 0, D_,
        KV, (long long)B_ * M_ * D_, 0, D_, nullptr, 0, B_ * M_, D_, D_, 1);
    // V projections
    gemm_bf16<<<dim3(4, 16, 2), 256, 0, stream>>>(
        mentions, 0, 0, D_, WVcat, (long long)D_ * D_, 0, D_,
        KV + 2 * 262144, (long long)B_ * M_ * D_, 0, D_, nullptr, 0, B_ * M_, D_, D_, 1);
    // Q projections (M = B*E = 512)
    gemm_bf16<<<dim3(4, 8, 2), 256, 0, stream>>>(
        ents, 0, 0, D_, WQcat, (long long)D_ * D_, 0, D_,
        Q2, (long long)B_ * E_ * D_, 0, D_, nullptr, 0, B_ * E_, D_, D_, 1);
    // VW[b,m,h,:] = V[b,m,h-slice] @ Wo[h-slice]; z = which*4 + h (ZD=4)
    gemm_bf16<<<dim3(4, 16, 8), 256, 0, stream>>>(
        KV + 2 * 262144, (long long)B_ * M_ * D_, DK_, D_,
        WOcat, (long long)D_ * D_, (long long)DK_ * D_, D_,
        VW2, (long long)B_ * M_ * H_ * D_, D_, H_ * D_,
        nullptr, 0, B_ * M_, D_, DK_, 4);

    // merged attention combine: grid z=0 rep_h, z=1 rep_t
    combine_kernel<<<dim3(E_, B_ * 4, 2), 256, 0, stream>>>(Q2, KV, VW2, mcnt, mlist, out);
}

// Round 4
// 175.650 us; speedup vs baseline: 3.1878x; 1.5835x over previous
//
#include <hip/hip_runtime.h>
#include <math.h>

#define B_ 8
#define N_ 224
#define E_ 64
#define M_ 128
#define S_ 32
#define D_ 256
#define IN_ 300
#define R_ 5
#define H_ 4
#define DK_ 64
#define OUTROWS (N_ + 2 * E_ * E_)   // 8416
#define CAP_ 192

typedef __attribute__((ext_vector_type(8))) short bf16x8;
typedef __attribute__((ext_vector_type(4))) float f32x4;

__device__ inline short f2bf(float f) {
    union { float f; unsigned u; } x; x.f = f;
    unsigned u = x.u;
    unsigned r = (u + 0x7fffu + ((u >> 16) & 1u)) >> 16;
    return (short)r;
}

// ---------------- pack all weights into bf16, TRANSPOSED [n][k], K-padded ----------------
// shorts layout: W1t [6][256][320]  (z 0..4 = Wr0[r], z5 = W00; k>=300 -> 0)   491,520
//               W2t [6][256][256]  (z 0..4 = Wr1[r], z5 = W01)                 393,216
//               WKt [2][256][256]  (h,t)                                       262,144
//               WVt [2][256][256]                                              262,144
//               WQt [2][256][256]                                              262,144
//               WOt [8][256][64]   (which*4+h; k local to head block)          131,072
#define PW_TOT 1802240
__global__ void pack_weights(short* __restrict__ Wb,
    const float* Wr0, const float* W00, const float* Wr1, const float* W01,
    const float* Wkh, const float* Wkt, const float* Wvh, const float* Wvt,
    const float* Wqh, const float* Wqt, const float* Woh, const float* Wot) {
    for (int i = blockIdx.x * 256 + threadIdx.x; i < PW_TOT; i += gridDim.x * 256) {
        float v; int j = i;
        if (j < 491520) {
            int z = j / 81920, rem = j % 81920, n = rem / 320, k = rem % 320;
            v = (k < IN_) ? (z < 5 ? Wr0[((size_t)z * IN_ + k) * D_ + n]
                                   : W00[(size_t)k * D_ + n]) : 0.f;
        } else if ((j -= 491520) < 393216) {
            int z = j / 65536, rem = j % 65536, n = rem / 256, k = rem % 256;
            v = z < 5 ? Wr1[((size_t)z * D_ + k) * D_ + n] : W01[(size_t)k * D_ + n];
        } else if ((j -= 393216) < 262144) {
            int z = j / 65536, rem = j % 65536, n = rem / 256, k = rem % 256;
            v = (z ? Wkt : Wkh)[(size_t)k * D_ + n];
        } else if ((j -= 262144) < 262144) {
            int z = j / 65536, rem = j % 65536, n = rem / 256, k = rem % 256;
            v = (z ? Wvt : Wvh)[(size_t)k * D_ + n];
        } else if ((j -= 262144) < 262144) {
            int z = j / 65536, rem = j % 65536, n = rem / 256, k = rem % 256;
            v = (z ? Wqt : Wqh)[(size_t)k * D_ + n];
        } else {
            j -= 262144;
            int z = j / 16384, rem = j % 16384, n = rem / 64, k = rem % 64;
            int which = z >> 2, h = z & 3;
            v = (which ? Wot : Woh)[((size_t)(h * 64 + k)) * D_ + n];
        }
        Wb[i] = f2bf(v);
    }
}

// ---------- build per-(b,n) edge lists + denominators (deterministic) ----------
__global__ __launch_bounds__(256) void build_edges(
    const float* __restrict__ adj, int* __restrict__ ecnt,
    int* __restrict__ elist, float* __restrict__ evals, float* __restrict__ den) {
    int bn = blockIdx.x;
    int b = bn / N_, n = bn % N_;
    int tid = threadIdx.x;
    __shared__ int sc[256];
    __shared__ float sv[256];
    int idxs[5]; float vals[5];
    int cloc = 0; float sloc = 0.f;
    for (int e = tid; e < R_ * N_; e += 256) {
        int r = e / N_, m = e % N_;
        float v = adj[(((size_t)(b * R_ + r)) * N_ + n) * N_ + m];
        if (v != 0.f) { idxs[cloc] = e; vals[cloc] = v; ++cloc; sloc += v; }
    }
    sc[tid] = cloc; sv[tid] = sloc;
    __syncthreads();
    for (int st = 1; st < 256; st <<= 1) {
        int add = (tid >= st) ? sc[tid - st] : 0;
        __syncthreads();
        sc[tid] += add;
        __syncthreads();
    }
    int off = sc[tid] - cloc;
    int total = sc[255];
    for (int st = 128; st > 0; st >>= 1) {
        if (tid < st) sv[tid] += sv[tid + st];
        __syncthreads();
    }
    size_t base = (size_t)bn * CAP_;
    for (int i = 0; i < cloc; ++i) {
        int p = off + i;
        if (p < CAP_) { elist[base + p] = idxs[i]; evals[base + p] = vals[i]; }
    }
    if (tid == 0) {
        ecnt[bn] = total < CAP_ ? total : CAP_;
        den[bn] = sv[0] + 1.0f;
    }
}

// ---------- AxW via edge gather, fused epilogue: relu((Σ val·xW + t)/den) ----------
__global__ __launch_bounds__(256) void axw_gather(
    const float* __restrict__ xW, const float* __restrict__ t,
    const int* __restrict__ ecnt, const int* __restrict__ elist,
    const float* __restrict__ evals, const float* __restrict__ den,
    float* __restrict__ out, long long out_bstride) {
    int bn = blockIdx.x;
    int b = bn / N_, n = bn % N_;
    int d = threadIdx.x;
    int c = ecnt[bn];
    const int* lst = elist + (size_t)bn * CAP_;
    const float* vls = evals + (size_t)bn * CAP_;
    float acc = 0.f;
#pragma unroll 4
    for (int k = 0; k < c; ++k) {
        int e = lst[k];
        float v = vls[k];
        int r = e / N_, m = e % N_;
        acc += v * xW[(((size_t)r * B_ + b) * N_ + m) * D_ + d];
    }
    float val = (acc + t[(size_t)bn * D_ + d]) / den[bn];
    out[(size_t)b * out_bstride + (size_t)n * D_ + d] = val > 0.f ? val : 0.f;
}

// ---------- bf16 MFMA GEMM: C = A(fp32)@Bt(bf16,[n][k]) (+bias), dual-z batching ----------
// block 256 = 4 waves, tile 64x64, BK=32. Nc fixed 256 via grid.x=4. Mr % 64 == 0.
__global__ __launch_bounds__(256) void gemm_bf16(
    const float* __restrict__ A, long long azs1, long long azs2, int lda,
    const short* __restrict__ Bt, long long bzs1, long long bzs2, int ldbk,
    float* __restrict__ C, long long czs1, long long czs2, int ldc,
    const float* __restrict__ bias0, long long b0zs, int nb0,
    const float* __restrict__ bias1,
    int Mr, int K, int ZD) {
    int z = blockIdx.z;
    int z1 = z / ZD, z2 = z % ZD;
    A  += (size_t)z1 * azs1 + (size_t)z2 * azs2;
    Bt += (size_t)z1 * bzs1 + (size_t)z2 * bzs2;
    C  += (size_t)z1 * czs1 + (size_t)z2 * czs2;
    const float* bias = bias0 ? (z1 < nb0 ? bias0 + (size_t)z1 * b0zs : bias1) : nullptr;

    __shared__ short As[64][40];
    __shared__ short Bs[64][40];
    int tid = threadIdx.x;
    int lane = tid & 63, wv = tid >> 6;
    int wr = wv >> 1, wc = wv & 1;
    int fr = lane & 15, fk = (lane >> 4) * 8;
    int row0 = blockIdx.y * 64, col0 = blockIdx.x * 64;
    int ar = tid >> 2, aq = (tid & 3) * 8;
    int bc = tid >> 2, bkq = (tid & 3) * 8;

    f32x4 acc00 = {0.f,0.f,0.f,0.f}, acc01 = acc00, acc10 = acc00, acc11 = acc00;

    for (int k0 = 0; k0 < K; k0 += 32) {
        bf16x8 av;
        if (k0 + aq + 8 <= K) {
            const float* ap = &A[(size_t)(row0 + ar) * lda + k0 + aq];
            float4 f1 = *(const float4*)ap;
            float4 f2 = *(const float4*)(ap + 4);
            av[0]=f2bf(f1.x); av[1]=f2bf(f1.y); av[2]=f2bf(f1.z); av[3]=f2bf(f1.w);
            av[4]=f2bf(f2.x); av[5]=f2bf(f2.y); av[6]=f2bf(f2.z); av[7]=f2bf(f2.w);
        } else {
#pragma unroll
            for (int j = 0; j < 8; ++j) {
                int gk = k0 + aq + j;
                av[j] = (gk < K) ? f2bf(A[(size_t)(row0 + ar) * lda + gk]) : (short)0;
            }
        }
        *(bf16x8*)&As[ar][aq] = av;

        // B pre-packed bf16 [n][k] (k padded to >= K rounded up to 32): one 16B load
        *(bf16x8*)&Bs[bc][bkq] =
            *(const bf16x8*)&Bt[(size_t)(col0 + bc) * ldbk + k0 + bkq];
        __syncthreads();

        bf16x8 a0 = *(bf16x8*)&As[wr * 32 + fr][fk];
        bf16x8 a1 = *(bf16x8*)&As[wr * 32 + 16 + fr][fk];
        bf16x8 b0 = *(bf16x8*)&Bs[wc * 32 + fr][fk];
        bf16x8 b1 = *(bf16x8*)&Bs[wc * 32 + 16 + fr][fk];
        acc00 = __builtin_amdgcn_mfma_f32_16x16x32_bf16(a0, b0, acc00, 0, 0, 0);
        acc01 = __builtin_amdgcn_mfma_f32_16x16x32_bf16(a0, b1, acc01, 0, 0, 0);
        acc10 = __builtin_amdgcn_mfma_f32_16x16x32_bf16(a1, b0, acc10, 0, 0, 0);
        acc11 = __builtin_amdgcn_mfma_f32_16x16x32_bf16(a1, b1, acc11, 0, 0, 0);
        __syncthreads();
    }

    int rbase = row0 + wr * 32 + (lane >> 4) * 4;
    int cbase = col0 + wc * 32 + fr;
    f32x4 accs[2][2] = {{acc00, acc01}, {acc10, acc11}};
#pragma unroll
    for (int mi = 0; mi < 2; ++mi) {
#pragma unroll
        for (int nj = 0; nj < 2; ++nj) {
            int cc = cbase + nj * 16;
            float bval = bias ? bias[cc] : 0.f;
#pragma unroll
            for (int r = 0; r < 4; ++r) {
                int cr = rbase + mi * 16 + r;
                C[(size_t)cr * ldc + cc] = accs[mi][nj][r] + bval;
            }
        }
    }
}

// ---------------- msr gather (float4) ----------------
__global__ void gather_msr(const float* __restrict__ sentences, const int* __restrict__ sid,
                           float* __restrict__ msr) {
    int idx = blockIdx.x * 256 + threadIdx.x;
    if (idx >= B_ * M_ * (D_ / 4)) return;
    int bm = idx >> 6, d4 = idx & 63;
    ((float4*)msr)[idx] = ((const float4*)(sentences + (size_t)sid[bm] * D_))[d4];
}
__global__ void mention_lists(const int* __restrict__ eid, int* __restrict__ cnt,
                              int* __restrict__ mlist) {
    int t = blockIdx.x * blockDim.x + threadIdx.x;
    if (t >= B_ * E_) return;
    int b = t / E_, i = t % E_;
    int c = 0;
    for (int m = 0; m < M_; ++m)
        if (eid[b * M_ + m] == i) mlist[(size_t)t * M_ + c++] = m;
    cnt[t] = c;
}

// ------------- per (b, masked-entity, q-group, rep) attention combine -------------
// grid (E_, B_*4, 2). z=0: rep_h (me = outer i, q = inner j, row = me*E+q)
//                     z=1: rep_t (me = inner j, q = outer i, row = q*E+me)
// Fast path c<=2 (data: exactly 2 mentions/entity). LDS 8.7 KB -> high occupancy.
__global__ __launch_bounds__(256) void combine_kernel(
    const float* __restrict__ Qb, const float* __restrict__ Kb,
    const float* __restrict__ VWb, const int* __restrict__ cnt,
    const int* __restrict__ mlist, float* __restrict__ out) {
    int z = blockIdx.z;
    const float* Q  = Qb  + (size_t)z * (B_ * E_ * D_);
    const float* K  = Kb  + (size_t)z * (B_ * M_ * D_);
    const float* VW = VWb + (size_t)z * (B_ * M_ * H_ * D_);
    int baserow = N_ + z * (E_ * E_);
    int me = blockIdx.x;
    int b = blockIdx.y >> 2, qg = blockIdx.y & 3;
    int qbase = qg * 16;
    int tid = threadIdx.x;
    int dq = tid & 63;
    __shared__ float sVW[2][H_ * D_];
    __shared__ float sS[16][H_][2];
    int c = cnt[b * E_ + me];
    const int* lst = mlist + (size_t)(b * E_ + me) * M_;

    if (c >= 1 && c <= 2) {
        for (int k = 0; k < c; ++k)
            ((float4*)sVW[k])[tid] =
                ((const float4*)(VW + ((size_t)b * M_ + lst[k]) * (H_ * D_)))[tid];
        if (tid < 16 * H_ * 2) {
            int k = tid & 1, hh = (tid >> 1) & 3, ql = tid >> 3;
            if (k < c) {
                const float4* Qr = (const float4*)(Q + ((size_t)b * E_ + qbase + ql) * D_ + hh * DK_);
                const float4* Kr = (const float4*)(K + ((size_t)b * M_ + lst[k]) * D_ + hh * DK_);
                float dot = 0.f;
#pragma unroll
                for (int t4 = 0; t4 < 16; ++t4) {
                    float4 qv = Qr[t4], kv = Kr[t4];
                    dot += qv.x * kv.x + qv.y * kv.y + qv.z * kv.z + qv.w * kv.w;
                }
                sS[ql][hh][k] = dot * 0.125f;
            }
        }
        __syncthreads();
        if (tid < 64) {
            int hh = tid & 3, ql = tid >> 2;
            float mx = sS[ql][hh][0];
            for (int k = 1; k < c; ++k) mx = fmaxf(mx, sS[ql][hh][k]);
            float w[2]; float sm = 0.f;
            for (int k = 0; k < c; ++k) { w[k] = __expf(sS[ql][hh][k] - mx); sm += w[k]; }
            float inv = 1.f / sm;
            for (int k = 0; k < c; ++k) sS[ql][hh][k] = w[k] * inv;
        }
        __syncthreads();
        for (int qq = tid >> 6; qq < 16; qq += 4) {
            float4 acc = make_float4(0.f, 0.f, 0.f, 0.f);
#pragma unroll
            for (int hh = 0; hh < H_; ++hh)
                for (int k = 0; k < c; ++k) {
                    float w = sS[qq][hh][k];
                    float4 v = *(const float4*)&sVW[k][hh * D_ + dq * 4];
                    acc.x += w * v.x; acc.y += w * v.y; acc.z += w * v.z; acc.w += w * v.w;
                }
            int q = qbase + qq;
            int row = z ? (q * E_ + me) : (me * E_ + q);
            *(float4*)&out[((size_t)b * OUTROWS + baserow + row) * D_ + dq * 4] = acc;
        }
    } else if (c == 0) {
        // fully masked -> uniform softmax over all M mentions
        float s = 0.f;
        for (int m = 0; m < M_; ++m)
            for (int hh = 0; hh < H_; ++hh)
                s += VW[((size_t)b * M_ + m) * (H_ * D_) + hh * D_ + tid];
        sVW[0][tid] = s * (1.0f / M_);
        __syncthreads();
        for (int qq = tid >> 6; qq < 16; qq += 4) {
            float4 v = *(const float4*)&sVW[0][dq * 4];
            int q = qbase + qq;
            int row = z ? (q * E_ + me) : (me * E_ + q);
            *(float4*)&out[((size_t)b * OUTROWS + baserow + row) * D_ + dq * 4] = v;
        }
    } else {
        // general 3-pass fallback (never hit with this data; correctness parachute)
        if (tid < 64) {
            int hh = tid & 3, ql = tid >> 2;
            const float* Qrow = Q + ((size_t)b * E_ + qbase + ql) * D_ + hh * DK_;
            float mx = -1e30f;
            for (int k = 0; k < c; ++k) {
                const float* Krow = K + ((size_t)b * M_ + lst[k]) * D_ + hh * DK_;
                float dot = 0.f;
                for (int kk = 0; kk < DK_; ++kk) dot += Qrow[kk] * Krow[kk];
                mx = fmaxf(mx, dot * 0.125f);
            }
            float sm = 0.f;
            for (int k = 0; k < c; ++k) {
                const float* Krow = K + ((size_t)b * M_ + lst[k]) * D_ + hh * DK_;
                float dot = 0.f;
                for (int kk = 0; kk < DK_; ++kk) dot += Qrow[kk] * Krow[kk];
                sm += __expf(dot * 0.125f - mx);
            }
            sS[ql][hh][0] = mx;
            sS[ql][hh][1] = sm;
        }
        __syncthreads();
        for (int qq = tid >> 6; qq < 16; qq += 4) {
            float4 acc = make_float4(0.f, 0.f, 0.f, 0.f);
            for (int hh = 0; hh < H_; ++hh) {
                float mx = sS[qq][hh][0], inv = 1.f / sS[qq][hh][1];
                const float* Qrow = Q + ((size_t)b * E_ + qbase + qq) * D_ + hh * DK_;
                for (int k = 0; k < c; ++k) {
                    const float* Krow = K + ((size_t)b * M_ + lst[k]) * D_ + hh * DK_;
                    float dot = 0.f;
                    for (int kk = 0; kk < DK_; ++kk) dot += Qrow[kk] * Krow[kk];
                    float w = __expf(dot * 0.125f - mx) * inv;
                    const float4 v = *(const float4*)&VW[((size_t)b * M_ + lst[k]) * (H_ * D_) + hh * D_ + dq * 4];
                    acc.x += w * v.x; acc.y += w * v.y; acc.z += w * v.z; acc.w += w * v.w;
                }
            }
            int q = qbase + qq;
            int row = z ? (q * E_ + me) : (me * E_ + q);
            *(float4*)&out[((size_t)b * OUTROWS + baserow + row) * D_ + dq * 4] = acc;
        }
    }
}

extern "C" void kernel_launch(void* const* d_in, const int* in_sizes, int n_in,
                              void* d_out, int out_size, void* d_ws, size_t ws_size,
                              hipStream_t stream) {
    const float* nodes     = (const float*)d_in[0];
    const float* adj       = (const float*)d_in[1];
    const float* mentions  = (const float*)d_in[2];
    const float* sentences = (const float*)d_in[3];
    const float* Wr0 = (const float*)d_in[4];
    const float* br0 = (const float*)d_in[5];
    const float* Wr1 = (const float*)d_in[6];
    const float* br1 = (const float*)d_in[7];
    const float* W00 = (const float*)d_in[8];
    const float* b00 = (const float*)d_in[9];
    const float* W01 = (const float*)d_in[10];
    const float* b01 = (const float*)d_in[11];
    const float* Wq_h = (const float*)d_in[12];
    const float* Wk_h = (const float*)d_in[13];
    const float* Wv_h = (const float*)d_in[14];
    const float* Wo_h = (const float*)d_in[15];
    const float* Wq_t = (const float*)d_in[16];
    const float* Wk_t = (const float*)d_in[17];
    const float* Wv_t = (const float*)d_in[18];
    const float* Wo_t = (const float*)d_in[19];
    const int* info_eid = (const int*)d_in[20];
    const int* info_sid = (const int*)d_in[21];
    float* out  = (float*)d_out;
    float* pool = (float*)d_ws;

    // ---- stage 1 region (floats, offset 0) ----
    float* xW  = pool;                       // (6,B,N,D): z0..4 xW slices, z5 = tb
    float* tb  = pool + 2293760;             // (B,N,D)  458,752 (contiguous with xW)
    float* h   = pool + 2752512;             // (B,N,D)  458,752
    float* den = pool + 3211264;             // 1,792
    int*   elist = (int*)(pool + 3213056);   // 344,064
    float* evals = pool + 3557120;           // 344,064
    int*   ecnt  = (int*)(pool + 3901184);   // 1,792  -> stage1 ends 3,902,976
    // ---- stage 2 region (overlays stage 1 once consumed) ----
    float* msr = pool;                       // (B,M,D)        262,144
    float* KV  = pool + 262144;              // [Kh,Kt,Vh,Vt]  1,048,576
    float* Q2  = pool + 1310720;             // [which][b][E][D] 524,288
    float* VW2 = pool + 1835008;             // [VWh,VWt]      2,097,152 -> ends 3,932,160
    // ---- persistent region (after both stages) ----
    int*   mcnt  = (int*)(pool + 3932160);   // 512
    int*   mlist = (int*)(pool + 3932672);   // 65,536
    short* Wb    = (short*)(pool + 3998208); // 1,802,240 shorts = 901,120 floats
    // total: 4,899,328 floats (~19.6 MB)

    // packed bf16 weight offsets (shorts)
    short* W1t = Wb;                 // [6][256][320]
    short* W2t = Wb + 491520;        // [6][256][256]
    short* WKt = Wb + 884736;        // [2][256][256]
    short* WVt = Wb + 1146880;
    short* WQt = Wb + 1409024;
    short* WOt = Wb + 1671168;       // [8][256][64]

    pack_weights<<<2048, 256, 0, stream>>>(Wb, Wr0, W00, Wr1, W01,
                                           Wk_h, Wk_t, Wv_h, Wv_t,
                                           Wq_h, Wq_t, Wo_h, Wo_t);
    build_edges<<<B_ * N_, 256, 0, stream>>>(adj, ecnt, elist, evals, den);
    mention_lists<<<2, 256, 0, stream>>>(info_eid, mcnt, mlist);

    // L1: z=0..4 -> xW slices, z=5 -> tb. bias: br0[z] for z<5 else b00.
    gemm_bf16<<<dim3(4, 28, 6), 256, 0, stream>>>(
        nodes, 0, 0, IN_, W1t, 81920, 0, 320,
        xW, (long long)B_ * N_ * D_, 0, D_,
        br0, D_, 5, b00, B_ * N_, IN_, 1);
    axw_gather<<<B_ * N_, 256, 0, stream>>>(xW, tb, ecnt, elist, evals, den, h,
                                            (long long)N_ * D_);
    // L2
    gemm_bf16<<<dim3(4, 28, 6), 256, 0, stream>>>(
        h, 0, 0, D_, W2t, 65536, 0, D_,
        xW, (long long)B_ * N_ * D_, 0, D_,
        br1, D_, 5, b01, B_ * N_, D_, 1);
    axw_gather<<<B_ * N_, 256, 0, stream>>>(xW, tb, ecnt, elist, evals, den, out,
                                            (long long)OUTROWS * D_);

    gather_msr<<<B_ * M_ * (D_ / 4) / 256, 256, 0, stream>>>(sentences, info_sid, msr);

    // K projections: z in {h,t}
    gemm_bf16<<<dim3(4, 16, 2), 256, 0, stream>>>(
        msr, 0, 0, D_, WKt, 65536, 0, D_,
        KV, (long long)B_ * M_ * D_, 0, D_,
        nullptr, 0, 0, nullptr, B_ * M_, D_, 1);
    // V projections
    gemm_bf16<<<dim3(4, 16, 2), 256, 0, stream>>>(
        mentions, 0, 0, D_, WVt, 65536, 0, D_,
        KV + 2 * 262144, (long long)B_ * M_ * D_, 0, D_,
        nullptr, 0, 0, nullptr, B_ * M_, D_, 1);
    // Q projections straight from `out` entity rows: z = b*2 + which (ZD=2)
    gemm_bf16<<<dim3(4, 1, 16), 256, 0, stream>>>(
        out, (long long)OUTROWS * D_, 0, D_, WQt, 0, 65536, D_,
        Q2, (long long)E_ * D_, (long long)B_ * E_ * D_, D_,
        nullptr, 0, 0, nullptr, E_, D_, 2);
    // VW[b,m,h,:] = V[b,m,h-slice] @ Wo[h-slice]; z = which*4 + h (ZD=4)
    gemm_bf16<<<dim3(4, 16, 8), 256, 0, stream>>>(
        KV + 2 * 262144, (long long)B_ * M_ * D_, DK_, D_,
        WOt, 65536, 16384, DK_,
        VW2, (long long)B_ * M_ * H_ * D_, D_, H_ * D_,
        nullptr, 0, 0, nullptr, B_ * M_, DK_, 4);

    // merged attention combine: z=0 rep_h, z=1 rep_t
    combine_kernel<<<dim3(E_, B_ * 4, 2), 256, 0, stream>>>(Q2, KV, VW2, mcnt, mlist, out);
}

// Round 5
// 166.721 us; speedup vs baseline: 3.3586x; 1.0536x over previous
//
#include <hip/hip_runtime.h>
#include <math.h>

#define B_ 8
#define N_ 224
#define E_ 64
#define M_ 128
#define S_ 32
#define D_ 256
#define IN_ 300
#define R_ 5
#define H_ 4
#define DK_ 64
#define OUTROWS (N_ + 2 * E_ * E_)   // 8416
#define CAP_ 192

typedef __attribute__((ext_vector_type(8))) short bf16x8;
typedef __attribute__((ext_vector_type(4))) float f32x4;

__device__ inline short f2bf(float f) {
    union { float f; unsigned u; } x; x.f = f;
    unsigned u = x.u;
    unsigned r = (u + 0x7fffu + ((u >> 16) & 1u)) >> 16;
    return (short)r;
}

// ---------------- pack all weights into bf16, TRANSPOSED [n][k], K-padded ----------------
// 32x32 LDS tile transpose: coalesced reads (n contiguous) AND coalesced writes (k contiguous).
// shorts layout: W1t [6][256][320]  (z 0..4 = Wr0[r], z5 = W00; k>=300 -> 0)   491,520
//               W2t [6][256][256]  (z 0..4 = Wr1[r], z5 = W01)                 393,216
//               WKt [2][256][256]  WVt [2][256][256]  WQt [2][256][256]        262,144 each
//               WOt [8][256][64]   (which*4+h; k local to head block)          131,072
// tiles: s0 480 | s1 384 | s2 128 | s3 128 | s4 128 | s5 128  -> 1376 blocks
__global__ __launch_bounds__(256) void pack_weights(short* __restrict__ Wb,
    const float* Wr0, const float* W00, const float* Wr1, const float* W01,
    const float* Wkh, const float* Wkt, const float* Wvh, const float* Wvt,
    const float* Wqh, const float* Wqt, const float* Woh, const float* Wot) {
    __shared__ short T[32][33];
    int t = blockIdx.x;
    const float* src; short* outp; int outld, klim, n0, k0;
    if (t < 480) {
        int z = t / 80, tt = t % 80;
        n0 = (tt & 7) * 32; k0 = (tt >> 3) * 32;
        outp = Wb + (size_t)z * 81920; outld = 320; klim = IN_;
        src = (z < 5) ? Wr0 + (size_t)z * IN_ * D_ : W00;
    } else if (t < 864) {
        int l = t - 480, z = l / 64, tt = l % 64;
        n0 = (tt & 7) * 32; k0 = (tt >> 3) * 32;
        outp = Wb + 491520 + (size_t)z * 65536; outld = 256; klim = 256;
        src = (z < 5) ? Wr1 + (size_t)z * D_ * D_ : W01;
    } else if (t < 992) {
        int l = t - 864, z = l / 64, tt = l % 64;
        n0 = (tt & 7) * 32; k0 = (tt >> 3) * 32;
        outp = Wb + 884736 + (size_t)z * 65536; outld = 256; klim = 256;
        src = z ? Wkt : Wkh;
    } else if (t < 1120) {
        int l = t - 992, z = l / 64, tt = l % 64;
        n0 = (tt & 7) * 32; k0 = (tt >> 3) * 32;
        outp = Wb + 1146880 + (size_t)z * 65536; outld = 256; klim = 256;
        src = z ? Wvt : Wvh;
    } else if (t < 1248) {
        int l = t - 1120, z = l / 64, tt = l % 64;
        n0 = (tt & 7) * 32; k0 = (tt >> 3) * 32;
        outp = Wb + 1409024 + (size_t)z * 65536; outld = 256; klim = 256;
        src = z ? Wqt : Wqh;
    } else {
        int l = t - 1248, z = l / 16, tt = l % 16;
        n0 = (tt & 7) * 32; k0 = (tt >> 3) * 32;
        outp = Wb + 1671168 + (size_t)z * 16384; outld = 64; klim = 64;
        int which = z >> 2, h = z & 3;
        src = (which ? Wot : Woh) + (size_t)(h * 64) * D_;
    }
    int tid = threadIdx.x, tx = tid & 31, ty = tid >> 5;
#pragma unroll
    for (int i = 0; i < 4; ++i) {
        int k = k0 + ty + 8 * i;
        float v = (k < klim) ? src[(size_t)k * D_ + n0 + tx] : 0.f;
        T[tx][ty + 8 * i] = f2bf(v);
    }
    __syncthreads();
#pragma unroll
    for (int i = 0; i < 4; ++i) {
        int n = ty + 8 * i;
        outp[(size_t)(n0 + n) * outld + k0 + tx] = T[n][tx];
    }
}

// ---------- build per-(b,n) edge lists + denominators (deterministic) ----------
__global__ __launch_bounds__(256) void build_edges(
    const float* __restrict__ adj, int* __restrict__ ecnt,
    int* __restrict__ elist, float* __restrict__ evals, float* __restrict__ den) {
    int bn = blockIdx.x;
    int b = bn / N_, n = bn % N_;
    int tid = threadIdx.x;
    __shared__ int sc[256];
    __shared__ float sv[256];
    int idxs[5]; float vals[5];
    int cloc = 0; float sloc = 0.f;
    for (int e = tid; e < R_ * N_; e += 256) {
        int r = e / N_, m = e % N_;
        float v = adj[(((size_t)(b * R_ + r)) * N_ + n) * N_ + m];
        if (v != 0.f) { idxs[cloc] = e; vals[cloc] = v; ++cloc; sloc += v; }
    }
    sc[tid] = cloc; sv[tid] = sloc;
    __syncthreads();
    for (int st = 1; st < 256; st <<= 1) {
        int add = (tid >= st) ? sc[tid - st] : 0;
        __syncthreads();
        sc[tid] += add;
        __syncthreads();
    }
    int off = sc[tid] - cloc;
    int total = sc[255];
    for (int st = 128; st > 0; st >>= 1) {
        if (tid < st) sv[tid] += sv[tid + st];
        __syncthreads();
    }
    size_t base = (size_t)bn * CAP_;
    for (int i = 0; i < cloc; ++i) {
        int p = off + i;
        if (p < CAP_) { elist[base + p] = idxs[i]; evals[base + p] = vals[i]; }
    }
    if (tid == 0) {
        ecnt[bn] = total < CAP_ ? total : CAP_;
        den[bn] = sv[0] + 1.0f;
    }
}

// ---------- AxW via edge gather (float4), fused epilogue: relu((Σ val·xW + t)/den) ----------
// 4 rows per 256-thread block; 64 lanes per row, float4 each.
__global__ __launch_bounds__(256) void axw_gather(
    const float* __restrict__ xW, const float* __restrict__ t,
    const int* __restrict__ ecnt, const int* __restrict__ elist,
    const float* __restrict__ evals, const float* __restrict__ den,
    float* __restrict__ out, long long out_bstride) {
    int bn = blockIdx.x * 4 + (threadIdx.x >> 6);
    int dq = threadIdx.x & 63;
    int b = bn / N_, n = bn % N_;
    int c = ecnt[bn];
    const int* lst = elist + (size_t)bn * CAP_;
    const float* vls = evals + (size_t)bn * CAP_;
    float4 acc = make_float4(0.f, 0.f, 0.f, 0.f);
#pragma unroll 2
    for (int k = 0; k < c; ++k) {
        int e = lst[k];
        float v = vls[k];
        int r = e / N_, m = e % N_;
        float4 x = ((const float4*)&xW[(((size_t)r * B_ + b) * N_ + m) * D_])[dq];
        acc.x += v * x.x; acc.y += v * x.y; acc.z += v * x.z; acc.w += v * x.w;
    }
    float4 tv = ((const float4*)&t[(size_t)bn * D_])[dq];
    float inv = 1.f / den[bn];
    float4 o;
    o.x = fmaxf((acc.x + tv.x) * inv, 0.f);
    o.y = fmaxf((acc.y + tv.y) * inv, 0.f);
    o.z = fmaxf((acc.z + tv.z) * inv, 0.f);
    o.w = fmaxf((acc.w + tv.w) * inv, 0.f);
    ((float4*)&out[(size_t)b * out_bstride + (size_t)n * D_])[dq] = o;
}

// ---------- bf16 MFMA GEMM: C = A(fp32)@Bt(bf16,[n][k]) (+bias), BK=64, dual-z ----------
// block 256 = 4 waves, tile 64x64. Nc = 256 via grid.x; Mr covered exactly by grid.y.
// arows: optional A row indirection (gather fused into the GEMM).
__global__ __launch_bounds__(256) void gemm_bf16(
    const float* __restrict__ A, const int* __restrict__ arows,
    long long azs1, long long azs2, int lda,
    const short* __restrict__ Bt, long long bzs1, long long bzs2, int ldbk,
    float* __restrict__ C, long long czs1, long long czs2, int ldc,
    const float* __restrict__ bias0, long long b0zs, int nb0,
    const float* __restrict__ bias1,
    int Kloop, int Kreal, int ZD) {
    int z = blockIdx.z;
    int z1 = z / ZD, z2 = z % ZD;
    A  += (size_t)z1 * azs1 + (size_t)z2 * azs2;
    Bt += (size_t)z1 * bzs1 + (size_t)z2 * bzs2;
    C  += (size_t)z1 * czs1 + (size_t)z2 * czs2;
    const float* bias = bias0 ? (z1 < nb0 ? bias0 + (size_t)z1 * b0zs : bias1) : nullptr;

    __shared__ short As[64][72];
    __shared__ short Bs[64][72];
    int tid = threadIdx.x;
    int lane = tid & 63, wv = tid >> 6;
    int wr = wv >> 1, wc = wv & 1;
    int fr = lane & 15, fk = (lane >> 4) * 8;
    int row0 = blockIdx.y * 64, col0 = blockIdx.x * 64;
    int ar = tid >> 2, aq = (tid & 3) * 16;
    int bc = tid >> 2, bkq = (tid & 3) * 16;
    int arow = row0 + ar;
    const float* Ap = A + (size_t)(arows ? arows[arow] : arow) * lda;
    const short* Bp = Bt + (size_t)(col0 + bc) * ldbk;

    f32x4 acc00 = {0.f,0.f,0.f,0.f}, acc01 = acc00, acc10 = acc00, acc11 = acc00;

    for (int k0 = 0; k0 < Kloop; k0 += 64) {
        int ka = k0 + aq;
        bf16x8 av0, av1;
        if (ka + 16 <= Kreal) {
            float4 f0 = *(const float4*)(Ap + ka);
            float4 f1 = *(const float4*)(Ap + ka + 4);
            float4 f2 = *(const float4*)(Ap + ka + 8);
            float4 f3 = *(const float4*)(Ap + ka + 12);
            av0[0]=f2bf(f0.x); av0[1]=f2bf(f0.y); av0[2]=f2bf(f0.z); av0[3]=f2bf(f0.w);
            av0[4]=f2bf(f1.x); av0[5]=f2bf(f1.y); av0[6]=f2bf(f1.z); av0[7]=f2bf(f1.w);
            av1[0]=f2bf(f2.x); av1[1]=f2bf(f2.y); av1[2]=f2bf(f2.z); av1[3]=f2bf(f2.w);
            av1[4]=f2bf(f3.x); av1[5]=f2bf(f3.y); av1[6]=f2bf(f3.z); av1[7]=f2bf(f3.w);
        } else {
#pragma unroll
            for (int j = 0; j < 8; ++j) {
                int gk = ka + j;
                av0[j] = (gk < Kreal) ? f2bf(Ap[gk]) : (short)0;
            }
#pragma unroll
            for (int j = 0; j < 8; ++j) {
                int gk = ka + 8 + j;
                av1[j] = (gk < Kreal) ? f2bf(Ap[gk]) : (short)0;
            }
        }
        *(bf16x8*)&As[ar][aq]     = av0;
        *(bf16x8*)&As[ar][aq + 8] = av1;
        *(bf16x8*)&Bs[bc][bkq]     = *(const bf16x8*)&Bp[k0 + bkq];
        *(bf16x8*)&Bs[bc][bkq + 8] = *(const bf16x8*)&Bp[k0 + bkq + 8];
        __syncthreads();
#pragma unroll
        for (int ks = 0; ks < 2; ++ks) {
            int ko = ks * 32 + fk;
            bf16x8 a0 = *(bf16x8*)&As[wr * 32 + fr][ko];
            bf16x8 a1 = *(bf16x8*)&As[wr * 32 + 16 + fr][ko];
            bf16x8 b0 = *(bf16x8*)&Bs[wc * 32 + fr][ko];
            bf16x8 b1 = *(bf16x8*)&Bs[wc * 32 + 16 + fr][ko];
            acc00 = __builtin_amdgcn_mfma_f32_16x16x32_bf16(a0, b0, acc00, 0, 0, 0);
            acc01 = __builtin_amdgcn_mfma_f32_16x16x32_bf16(a0, b1, acc01, 0, 0, 0);
            acc10 = __builtin_amdgcn_mfma_f32_16x16x32_bf16(a1, b0, acc10, 0, 0, 0);
            acc11 = __builtin_amdgcn_mfma_f32_16x16x32_bf16(a1, b1, acc11, 0, 0, 0);
        }
        __syncthreads();
    }

    int rbase = row0 + wr * 32 + (lane >> 4) * 4;
    int cbase = col0 + wc * 32 + fr;
    f32x4 accs[2][2] = {{acc00, acc01}, {acc10, acc11}};
#pragma unroll
    for (int mi = 0; mi < 2; ++mi) {
#pragma unroll
        for (int nj = 0; nj < 2; ++nj) {
            int cc = cbase + nj * 16;
            float bval = bias ? bias[cc] : 0.f;
#pragma unroll
            for (int r = 0; r < 4; ++r) {
                int cr = rbase + mi * 16 + r;
                C[(size_t)cr * ldc + cc] = accs[mi][nj][r] + bval;
            }
        }
    }
}

__global__ void mention_lists(const int* __restrict__ eid, int* __restrict__ cnt,
                              int* __restrict__ mlist) {
    int t = blockIdx.x * blockDim.x + threadIdx.x;
    if (t >= B_ * E_) return;
    int b = t / E_, i = t % E_;
    int c = 0;
    for (int m = 0; m < M_; ++m)
        if (eid[b * M_ + m] == i) mlist[(size_t)t * M_ + c++] = m;
    cnt[t] = c;
}

// ------------- per (b, masked-entity, q-group, rep) attention combine -------------
// grid (E_, B_*4, 2). z=0: rep_h (me = outer i, q = inner j, row = me*E+q)
//                     z=1: rep_t (me = inner j, q = outer i, row = q*E+me)
__global__ __launch_bounds__(256) void combine_kernel(
    const float* __restrict__ Qb, const float* __restrict__ Kb,
    const float* __restrict__ VWb, const int* __restrict__ cnt,
    const int* __restrict__ mlist, float* __restrict__ out) {
    int z = blockIdx.z;
    const float* Q  = Qb  + (size_t)z * (B_ * E_ * D_);
    const float* K  = Kb  + (size_t)z * (B_ * M_ * D_);
    const float* VW = VWb + (size_t)z * (B_ * M_ * H_ * D_);
    int baserow = N_ + z * (E_ * E_);
    int me = blockIdx.x;
    int b = blockIdx.y >> 2, qg = blockIdx.y & 3;
    int qbase = qg * 16;
    int tid = threadIdx.x;
    int dq = tid & 63;
    __shared__ float sVW[2][H_ * D_];
    __shared__ float sS[16][H_][2];
    int c = cnt[b * E_ + me];
    const int* lst = mlist + (size_t)(b * E_ + me) * M_;

    if (c >= 1 && c <= 2) {
        for (int k = 0; k < c; ++k)
            ((float4*)sVW[k])[tid] =
                ((const float4*)(VW + ((size_t)b * M_ + lst[k]) * (H_ * D_)))[tid];
        if (tid < 16 * H_ * 2) {
            int k = tid & 1, hh = (tid >> 1) & 3, ql = tid >> 3;
            if (k < c) {
                const float4* Qr = (const float4*)(Q + ((size_t)b * E_ + qbase + ql) * D_ + hh * DK_);
                const float4* Kr = (const float4*)(K + ((size_t)b * M_ + lst[k]) * D_ + hh * DK_);
                float dot = 0.f;
#pragma unroll
                for (int t4 = 0; t4 < 16; ++t4) {
                    float4 qv = Qr[t4], kv = Kr[t4];
                    dot += qv.x * kv.x + qv.y * kv.y + qv.z * kv.z + qv.w * kv.w;
                }
                sS[ql][hh][k] = dot * 0.125f;
            }
        }
        __syncthreads();
        if (tid < 64) {
            int hh = tid & 3, ql = tid >> 2;
            float mx = sS[ql][hh][0];
            for (int k = 1; k < c; ++k) mx = fmaxf(mx, sS[ql][hh][k]);
            float w[2]; float sm = 0.f;
            for (int k = 0; k < c; ++k) { w[k] = __expf(sS[ql][hh][k] - mx); sm += w[k]; }
            float inv = 1.f / sm;
            for (int k = 0; k < c; ++k) sS[ql][hh][k] = w[k] * inv;
        }
        __syncthreads();
        for (int qq = tid >> 6; qq < 16; qq += 4) {
            float4 acc = make_float4(0.f, 0.f, 0.f, 0.f);
#pragma unroll
            for (int hh = 0; hh < H_; ++hh)
                for (int k = 0; k < c; ++k) {
                    float w = sS[qq][hh][k];
                    float4 v = *(const float4*)&sVW[k][hh * D_ + dq * 4];
                    acc.x += w * v.x; acc.y += w * v.y; acc.z += w * v.z; acc.w += w * v.w;
                }
            int q = qbase + qq;
            int row = z ? (q * E_ + me) : (me * E_ + q);
            *(float4*)&out[((size_t)b * OUTROWS + baserow + row) * D_ + dq * 4] = acc;
        }
    } else if (c == 0) {
        float s = 0.f;
        for (int m = 0; m < M_; ++m)
            for (int hh = 0; hh < H_; ++hh)
                s += VW[((size_t)b * M_ + m) * (H_ * D_) + hh * D_ + tid];
        sVW[0][tid] = s * (1.0f / M_);
        __syncthreads();
        for (int qq = tid >> 6; qq < 16; qq += 4) {
            float4 v = *(const float4*)&sVW[0][dq * 4];
            int q = qbase + qq;
            int row = z ? (q * E_ + me) : (me * E_ + q);
            *(float4*)&out[((size_t)b * OUTROWS + baserow + row) * D_ + dq * 4] = v;
        }
    } else {
        // general fallback (correctness parachute)
        if (tid < 64) {
            int hh = tid & 3, ql = tid >> 2;
            const float* Qrow = Q + ((size_t)b * E_ + qbase + ql) * D_ + hh * DK_;
            float mx = -1e30f;
            for (int k = 0; k < c; ++k) {
                const float* Krow = K + ((size_t)b * M_ + lst[k]) * D_ + hh * DK_;
                float dot = 0.f;
                for (int kk = 0; kk < DK_; ++kk) dot += Qrow[kk] * Krow[kk];
                mx = fmaxf(mx, dot * 0.125f);
            }
            float sm = 0.f;
            for (int k = 0; k < c; ++k) {
                const float* Krow = K + ((size_t)b * M_ + lst[k]) * D_ + hh * DK_;
                float dot = 0.f;
                for (int kk = 0; kk < DK_; ++kk) dot += Qrow[kk] * Krow[kk];
                sm += __expf(dot * 0.125f - mx);
            }
            sS[ql][hh][0] = mx;
            sS[ql][hh][1] = sm;
        }
        __syncthreads();
        for (int qq = tid >> 6; qq < 16; qq += 4) {
            float4 acc = make_float4(0.f, 0.f, 0.f, 0.f);
            for (int hh = 0; hh < H_; ++hh) {
                float mx = sS[qq][hh][0], inv = 1.f / sS[qq][hh][1];
                const float* Qrow = Q + ((size_t)b * E_ + qbase + qq) * D_ + hh * DK_;
                for (int k = 0; k < c; ++k) {
                    const float* Krow = K + ((size_t)b * M_ + lst[k]) * D_ + hh * DK_;
                    float dot = 0.f;
                    for (int kk = 0; kk < DK_; ++kk) dot += Qrow[kk] * Krow[kk];
                    float w = __expf(dot * 0.125f - mx) * inv;
                    const float4 v = *(const float4*)&VW[((size_t)b * M_ + lst[k]) * (H_ * D_) + hh * D_ + dq * 4];
                    acc.x += w * v.x; acc.y += w * v.y; acc.z += w * v.z; acc.w += w * v.w;
                }
            }
            int q = qbase + qq;
            int row = z ? (q * E_ + me) : (me * E_ + q);
            *(float4*)&out[((size_t)b * OUTROWS + baserow + row) * D_ + dq * 4] = acc;
        }
    }
}

extern "C" void kernel_launch(void* const* d_in, const int* in_sizes, int n_in,
                              void* d_out, int out_size, void* d_ws, size_t ws_size,
                              hipStream_t stream) {
    const float* nodes     = (const float*)d_in[0];
    const float* adj       = (const float*)d_in[1];
    const float* mentions  = (const float*)d_in[2];
    const float* sentences = (const float*)d_in[3];
    const float* Wr0 = (const float*)d_in[4];
    const float* br0 = (const float*)d_in[5];
    const float* Wr1 = (const float*)d_in[6];
    const float* br1 = (const float*)d_in[7];
    const float* W00 = (const float*)d_in[8];
    const float* b00 = (const float*)d_in[9];
    const float* W01 = (const float*)d_in[10];
    const float* b01 = (const float*)d_in[11];
    const float* Wq_h = (const float*)d_in[12];
    const float* Wk_h = (const float*)d_in[13];
    const float* Wv_h = (const float*)d_in[14];
    const float* Wo_h = (const float*)d_in[15];
    const float* Wq_t = (const float*)d_in[16];
    const float* Wk_t = (const float*)d_in[17];
    const float* Wv_t = (const float*)d_in[18];
    const float* Wo_t = (const float*)d_in[19];
    const int* info_eid = (const int*)d_in[20];
    const int* info_sid = (const int*)d_in[21];
    float* out  = (float*)d_out;
    float* pool = (float*)d_ws;

    // ---- stage 1 region (floats, offset 0) ----
    float* xW  = pool;                       // (6,B,N,D): z0..4 xW slices, z5 = tb
    float* tb  = pool + 2293760;             // (B,N,D)  458,752 (contiguous with xW)
    float* h   = pool + 2752512;             // (B,N,D)  458,752
    float* den = pool + 3211264;             // 1,792
    int*   elist = (int*)(pool + 3213056);   // 344,064
    float* evals = pool + 3557120;           // 344,064
    int*   ecnt  = (int*)(pool + 3901184);   // 1,792  -> stage1 ends 3,902,976
    // ---- stage 2 region (overlays stage 1 once consumed) ----
    float* KV  = pool + 262144;              // [Kh,Kt,Vh,Vt]  1,048,576
    float* Q2  = pool + 1310720;             // [which][b][E][D] 524,288
    float* VW2 = pool + 1835008;             // [VWh,VWt]      2,097,152 -> ends 3,932,160
    // ---- persistent region ----
    int*   mcnt  = (int*)(pool + 3932160);   // 512
    int*   mlist = (int*)(pool + 3932672);   // 65,536
    short* Wb    = (short*)(pool + 3998208); // 1,802,240 shorts = 901,120 floats

    // packed bf16 weight offsets (shorts)
    short* W1t = Wb;                 // [6][256][320]
    short* W2t = Wb + 491520;        // [6][256][256]
    short* WKt = Wb + 884736;        // [2][256][256]
    short* WVt = Wb + 1146880;
    short* WQt = Wb + 1409024;
    short* WOt = Wb + 1671168;       // [8][256][64]

    pack_weights<<<1376, 256, 0, stream>>>(Wb, Wr0, W00, Wr1, W01,
                                           Wk_h, Wk_t, Wv_h, Wv_t,
                                           Wq_h, Wq_t, Wo_h, Wo_t);
    build_edges<<<B_ * N_, 256, 0, stream>>>(adj, ecnt, elist, evals, den);
    mention_lists<<<2, 256, 0, stream>>>(info_eid, mcnt, mlist);

    // L1: z=0..4 -> xW slices, z=5 -> tb. Kloop=320 (B zero-padded), Kreal=300.
    gemm_bf16<<<dim3(4, 28, 6), 256, 0, stream>>>(
        nodes, nullptr, 0, 0, IN_, W1t, 81920, 0, 320,
        xW, (long long)B_ * N_ * D_, 0, D_,
        br0, D_, 5, b00, 320, IN_, 1);
    axw_gather<<<B_ * N_ / 4, 256, 0, stream>>>(xW, tb, ecnt, elist, evals, den, h,
                                                (long long)N_ * D_);
    // L2
    gemm_bf16<<<dim3(4, 28, 6), 256, 0, stream>>>(
        h, nullptr, 0, 0, D_, W2t, 65536, 0, D_,
        xW, (long long)B_ * N_ * D_, 0, D_,
        br1, D_, 5, b01, D_, D_, 1);
    axw_gather<<<B_ * N_ / 4, 256, 0, stream>>>(xW, tb, ecnt, elist, evals, den, out,
                                                (long long)OUTROWS * D_);

    // K projections (msr gather fused via arows=info_sid): z in {h,t}
    gemm_bf16<<<dim3(4, 16, 2), 256, 0, stream>>>(
        sentences, info_sid, 0, 0, D_, WKt, 65536, 0, D_,
        KV, (long long)B_ * M_ * D_, 0, D_,
        nullptr, 0, 0, nullptr, D_, D_, 1);
    // V projections
    gemm_bf16<<<dim3(4, 16, 2), 256, 0, stream>>>(
        mentions, nullptr, 0, 0, D_, WVt, 65536, 0, D_,
        KV + 2 * 262144, (long long)B_ * M_ * D_, 0, D_,
        nullptr, 0, 0, nullptr, D_, D_, 1);
    // Q projections straight from `out` entity rows: z = b*2 + which (ZD=2)
    gemm_bf16<<<dim3(4, 1, 16), 256, 0, stream>>>(
        out, nullptr, (long long)OUTROWS * D_, 0, D_, WQt, 0, 65536, D_,
        Q2, (long long)E_ * D_, (long long)B_ * E_ * D_, D_,
        nullptr, 0, 0, nullptr, D_, D_, 2);
    // VW[b,m,h,:] = V[b,m,h-slice] @ Wo[h-slice]; z = which*4 + h (ZD=4)
    gemm_bf16<<<dim3(4, 16, 8), 256, 0, stream>>>(
        KV + 2 * 262144, nullptr, (long long)B_ * M_ * D_, DK_, D_,
        WOt, 65536, 16384, DK_,
        VW2, (long long)B_ * M_ * H_ * D_, D_, H_ * D_,
        nullptr, 0, 0, nullptr, DK_, DK_, 4);

    // merged attention combine: z=0 rep_h, z=1 rep_t
    combine_kernel<<<dim3(E_, B_ * 4, 2), 256, 0, stream>>>(Q2, KV, VW2, mcnt, mlist, out);
}

// Round 6
// 121.901 us; speedup vs baseline: 4.5934x; 1.3677x over previous
//
#include <hip/hip_runtime.h>
#include <math.h>

#define B_ 8
#define N_ 224
#define E_ 64
#define M_ 128
#define S_ 32
#define D_ 256
#define IN_ 300
#define R_ 5
#define H_ 4
#define DK_ 64
#define OUTROWS (N_ + 2 * E_ * E_)   // 8416
#define CAP_ 192
#define BN_ (B_ * N_)                // 1792

typedef __attribute__((ext_vector_type(8))) short bf16x8;
typedef __attribute__((ext_vector_type(8))) unsigned short u16x8;
typedef __attribute__((ext_vector_type(4))) float f32x4;

__device__ inline short f2bf(float f) {
    union { float f; unsigned u; } x; x.f = f;
    unsigned u = x.u;
    unsigned r = (u + 0x7fffu + ((u >> 16) & 1u)) >> 16;
    return (short)r;
}
__device__ inline float bf2f(unsigned short s) {
    union { unsigned u; float f; } x; x.u = ((unsigned)s) << 16; return x.f;
}

// ================= mega preprocessing kernel (block-range dispatch) =================
// [0,1376)            : pack weights -> bf16 transposed [n][k] (32x32 LDS transpose)
// [1376,3168)         : build edge lists + denoms (one block per (b,n))
// [3168,3170)         : mention lists
// [3170,4242)         : cvt inputs -> bf16 (nodesb padded 320, mentb, msrb gathered)
#define PRE_PACK 1376
#define PRE_EDGE (PRE_PACK + BN_)     // 3168
#define PRE_ML   (PRE_EDGE + 2)       // 3170
#define CVT_N    573440               // 1792*320
#define CVT_M    262144               // 1024*256
#define PRE_TOT  (PRE_ML + 1072)      // 1072*1024 = 1,097,728 elems

__global__ __launch_bounds__(256) void mega_pre(
    short* __restrict__ Wb,
    const float* Wr0, const float* W00, const float* Wr1, const float* W01,
    const float* Wkh, const float* Wkt, const float* Wvh, const float* Wvt,
    const float* Wqh, const float* Wqt, const float* Woh, const float* Wot,
    const float* __restrict__ adj, int* __restrict__ ecnt, int* __restrict__ elist,
    float* __restrict__ evals, float* __restrict__ den,
    const int* __restrict__ eid, int* __restrict__ mcnt, int* __restrict__ mlist,
    const float* __restrict__ nodes, const float* __restrict__ mentions,
    const float* __restrict__ sentences, const int* __restrict__ sid,
    short* __restrict__ nodesb, short* __restrict__ mentb, short* __restrict__ msrb) {
    __shared__ int smemi[528];   // 2112 B shared pool
    int blk = blockIdx.x, tid = threadIdx.x;

    if (blk < PRE_PACK) {
        // ---- weight pack: bf16 transposed [n][k] ----
        short (*T)[33] = (short(*)[33])smemi;
        int t = blk;
        const float* src; short* outp; int outld, klim, n0, k0;
        if (t < 480) {
            int z = t / 80, tt = t % 80;
            n0 = (tt & 7) * 32; k0 = (tt >> 3) * 32;
            outp = Wb + (size_t)z * 81920; outld = 320; klim = IN_;
            src = (z < 5) ? Wr0 + (size_t)z * IN_ * D_ : W00;
        } else if (t < 864) {
            int l = t - 480, z = l / 64, tt = l % 64;
            n0 = (tt & 7) * 32; k0 = (tt >> 3) * 32;
            outp = Wb + 491520 + (size_t)z * 65536; outld = 256; klim = 256;
            src = (z < 5) ? Wr1 + (size_t)z * D_ * D_ : W01;
        } else if (t < 992) {
            int l = t - 864, z = l / 64, tt = l % 64;
            n0 = (tt & 7) * 32; k0 = (tt >> 3) * 32;
            outp = Wb + 884736 + (size_t)z * 65536; outld = 256; klim = 256;
            src = z ? Wkt : Wkh;
        } else if (t < 1120) {
            int l = t - 992, z = l / 64, tt = l % 64;
            n0 = (tt & 7) * 32; k0 = (tt >> 3) * 32;
            outp = Wb + 1146880 + (size_t)z * 65536; outld = 256; klim = 256;
            src = z ? Wvt : Wvh;
        } else if (t < 1248) {
            int l = t - 1120, z = l / 64, tt = l % 64;
            n0 = (tt & 7) * 32; k0 = (tt >> 3) * 32;
            outp = Wb + 1409024 + (size_t)z * 65536; outld = 256; klim = 256;
            src = z ? Wqt : Wqh;
        } else {
            int l = t - 1248, z = l / 16, tt = l % 16;
            n0 = (tt & 7) * 32; k0 = (tt >> 3) * 32;
            outp = Wb + 1671168 + (size_t)z * 16384; outld = 64; klim = 64;
            int which = z >> 2, h = z & 3;
            src = (which ? Wot : Woh) + (size_t)(h * 64) * D_;
        }
        int tx = tid & 31, ty = tid >> 5;
#pragma unroll
        for (int i = 0; i < 4; ++i) {
            int k = k0 + ty + 8 * i;
            float v = (k < klim) ? src[(size_t)k * D_ + n0 + tx] : 0.f;
            T[tx][ty + 8 * i] = f2bf(v);
        }
        __syncthreads();
#pragma unroll
        for (int i = 0; i < 4; ++i) {
            int n = ty + 8 * i;
            outp[(size_t)(n0 + n) * outld + k0 + tx] = T[n][tx];
        }
    } else if (blk < PRE_EDGE) {
        // ---- edge lists + denoms ----
        int* sc = smemi;
        float* sv = (float*)&smemi[256];
        int bn = blk - PRE_PACK;
        int b = bn / N_, n = bn % N_;
        int idxs[5]; float vals[5];
        int cloc = 0; float sloc = 0.f;
        for (int e = tid; e < R_ * N_; e += 256) {
            int r = e / N_, m = e % N_;
            float v = adj[(((size_t)(b * R_ + r)) * N_ + n) * N_ + m];
            if (v != 0.f) { idxs[cloc] = e; vals[cloc] = v; ++cloc; sloc += v; }
        }
        sc[tid] = cloc; sv[tid] = sloc;
        __syncthreads();
        for (int st = 1; st < 256; st <<= 1) {
            int add = (tid >= st) ? sc[tid - st] : 0;
            __syncthreads();
            sc[tid] += add;
            __syncthreads();
        }
        int off = sc[tid] - cloc;
        int total = sc[255];
        for (int st = 128; st > 0; st >>= 1) {
            if (tid < st) sv[tid] += sv[tid + st];
            __syncthreads();
        }
        size_t base = (size_t)bn * CAP_;
        for (int i = 0; i < cloc; ++i) {
            int p = off + i;
            if (p < CAP_) { elist[base + p] = idxs[i]; evals[base + p] = vals[i]; }
        }
        if (tid == 0) {
            ecnt[bn] = total < CAP_ ? total : CAP_;
            den[bn] = sv[0] + 1.0f;
        }
    } else if (blk < PRE_ML) {
        int t = (blk - PRE_EDGE) * 256 + tid;
        if (t < B_ * E_) {
            int b = t / E_, i = t % E_;
            int c = 0;
            for (int m = 0; m < M_; ++m)
                if (eid[b * M_ + m] == i) mlist[(size_t)t * M_ + c++] = m;
            mcnt[t] = c;
        }
    } else {
        // ---- input cvt to bf16 ----
        int idx = (blk - PRE_ML) * 1024 + tid * 4;
#pragma unroll
        for (int j = 0; j < 4; ++j) {
            int i = idx + j;
            if (i < CVT_N) {
                int row = i / 320, k = i % 320;
                nodesb[i] = (k < IN_) ? f2bf(nodes[(size_t)row * IN_ + k]) : (short)0;
            } else if (i < CVT_N + CVT_M) {
                int i2 = i - CVT_N;
                mentb[i2] = f2bf(mentions[i2]);
            } else {
                int i3 = i - CVT_N - CVT_M;
                int bm = i3 >> 8, d = i3 & 255;
                msrb[i3] = f2bf(sentences[(size_t)sid[bm] * D_ + d]);
            }
        }
    }
}

// ---------- AxW via edge gather (bf16 xW), 4 gather-waves + LDS reduce ----------
// epilogue: relu((Σ val·xW + t)/den); t = xWb z=5
__global__ __launch_bounds__(256) void axw_gather(
    const short* __restrict__ xWb,
    const int* __restrict__ ecnt, const int* __restrict__ elist,
    const float* __restrict__ evals, const float* __restrict__ den,
    short* __restrict__ hb, float* __restrict__ out, long long out_bstride,
    short* __restrict__ entsb) {
    int bn = blockIdx.x;
    int b = bn / N_, n = bn % N_;
    int tid = threadIdx.x, wv = tid >> 6, dq = tid & 63;
    int c = ecnt[bn];
    const int* lst = elist + (size_t)bn * CAP_;
    const float* vls = evals + (size_t)bn * CAP_;
    float4 acc = make_float4(0.f, 0.f, 0.f, 0.f);
#pragma unroll 2
    for (int k = wv; k < c; k += 4) {
        int e = lst[k];
        float v = vls[k];
        int r = e / N_, m = e % N_;
        ushort4 x4 = *(const ushort4*)&xWb[((size_t)(r * BN_ + b * N_ + m)) * 256 + dq * 4];
        acc.x += v * bf2f(x4.x); acc.y += v * bf2f(x4.y);
        acc.z += v * bf2f(x4.z); acc.w += v * bf2f(x4.w);
    }
    __shared__ float4 red[4][64];
    red[wv][dq] = acc;
    __syncthreads();
    if (tid < 64) {
        float4 s0 = red[0][dq], s1 = red[1][dq], s2 = red[2][dq], s3 = red[3][dq];
        ushort4 t4 = *(const ushort4*)&xWb[((size_t)(5 * BN_ + bn)) * 256 + dq * 4];
        float inv = 1.f / den[bn];
        float4 o;
        o.x = fmaxf((s0.x + s1.x + s2.x + s3.x + bf2f(t4.x)) * inv, 0.f);
        o.y = fmaxf((s0.y + s1.y + s2.y + s3.y + bf2f(t4.y)) * inv, 0.f);
        o.z = fmaxf((s0.z + s1.z + s2.z + s3.z + bf2f(t4.z)) * inv, 0.f);
        o.w = fmaxf((s0.w + s1.w + s2.w + s3.w + bf2f(t4.w)) * inv, 0.f);
        if (hb) {
            ushort4 hw = { (unsigned short)f2bf(o.x), (unsigned short)f2bf(o.y),
                           (unsigned short)f2bf(o.z), (unsigned short)f2bf(o.w) };
            *(ushort4*)&hb[(size_t)bn * 256 + dq * 4] = hw;
        }
        if (out)
            *(float4*)&out[(size_t)b * out_bstride + (size_t)n * 256 + dq * 4] = o;
        if (entsb && n < E_) {
            ushort4 ew = { (unsigned short)f2bf(o.x), (unsigned short)f2bf(o.y),
                           (unsigned short)f2bf(o.z), (unsigned short)f2bf(o.w) };
            *(ushort4*)&entsb[((size_t)b * E_ + n) * 256 + dq * 4] = ew;
        }
    }
}

// ---------- all-bf16 MFMA GEMM: C(bf16) = A(bf16)@Bt(bf16 [n][k]) (+bias), BK=64 ----------
// block 256 = 4 waves, tile 64x64. Nc=256 via grid.x (or 64 for narrow), dual-z batching.
__global__ __launch_bounds__(256) void gemm_bf16(
    const short* __restrict__ A, long long azs1, long long azs2, int lda,
    const short* __restrict__ Bt, long long bzs1, long long bzs2, int ldbk,
    short* __restrict__ C, long long czs1, long long czs2, int ldc,
    const float* __restrict__ bias0, long long b0zs, int nb0,
    const float* __restrict__ bias1,
    int Kloop, int ZD) {
    int z = blockIdx.z;
    int z1 = z / ZD, z2 = z % ZD;
    A  += (size_t)z1 * azs1 + (size_t)z2 * azs2;
    Bt += (size_t)z1 * bzs1 + (size_t)z2 * bzs2;
    C  += (size_t)z1 * czs1 + (size_t)z2 * czs2;
    const float* bias = bias0 ? (z1 < nb0 ? bias0 + (size_t)z1 * b0zs : bias1) : nullptr;

    __shared__ short As[64][72];
    __shared__ short Bs[64][72];
    int tid = threadIdx.x;
    int lane = tid & 63, wv = tid >> 6;
    int wr = wv >> 1, wc = wv & 1;
    int fr = lane & 15, fk = (lane >> 4) * 8;
    int row0 = blockIdx.y * 64, col0 = blockIdx.x * 64;
    int ar = tid >> 2, aq = (tid & 3) * 16;
    int bc = tid >> 2, bkq = (tid & 3) * 16;
    const short* Ap = A + (size_t)(row0 + ar) * lda;
    const short* Bp = Bt + (size_t)(col0 + bc) * ldbk;

    f32x4 acc00 = {0.f,0.f,0.f,0.f}, acc01 = acc00, acc10 = acc00, acc11 = acc00;

    for (int k0 = 0; k0 < Kloop; k0 += 64) {
        *(bf16x8*)&As[ar][aq]     = *(const bf16x8*)&Ap[k0 + aq];
        *(bf16x8*)&As[ar][aq + 8] = *(const bf16x8*)&Ap[k0 + aq + 8];
        *(bf16x8*)&Bs[bc][bkq]     = *(const bf16x8*)&Bp[k0 + bkq];
        *(bf16x8*)&Bs[bc][bkq + 8] = *(const bf16x8*)&Bp[k0 + bkq + 8];
        __syncthreads();
#pragma unroll
        for (int ks = 0; ks < 2; ++ks) {
            int ko = ks * 32 + fk;
            bf16x8 a0 = *(bf16x8*)&As[wr * 32 + fr][ko];
            bf16x8 a1 = *(bf16x8*)&As[wr * 32 + 16 + fr][ko];
            bf16x8 b0 = *(bf16x8*)&Bs[wc * 32 + fr][ko];
            bf16x8 b1 = *(bf16x8*)&Bs[wc * 32 + 16 + fr][ko];
            acc00 = __builtin_amdgcn_mfma_f32_16x16x32_bf16(a0, b0, acc00, 0, 0, 0);
            acc01 = __builtin_amdgcn_mfma_f32_16x16x32_bf16(a0, b1, acc01, 0, 0, 0);
            acc10 = __builtin_amdgcn_mfma_f32_16x16x32_bf16(a1, b0, acc10, 0, 0, 0);
            acc11 = __builtin_amdgcn_mfma_f32_16x16x32_bf16(a1, b1, acc11, 0, 0, 0);
        }
        __syncthreads();
    }

    int rbase = row0 + wr * 32 + (lane >> 4) * 4;
    int cbase = col0 + wc * 32 + fr;
    f32x4 accs[2][2] = {{acc00, acc01}, {acc10, acc11}};
#pragma unroll
    for (int mi = 0; mi < 2; ++mi) {
#pragma unroll
        for (int nj = 0; nj < 2; ++nj) {
            int cc = cbase + nj * 16;
            float bval = bias ? bias[cc] : 0.f;
#pragma unroll
            for (int r = 0; r < 4; ++r) {
                int cr = rbase + mi * 16 + r;
                C[(size_t)cr * ldc + cc] = f2bf(accs[mi][nj][r] + bval);
            }
        }
    }
}

__device__ inline float dot64_bf(const short* q, const short* k) {
    float dot = 0.f;
#pragma unroll
    for (int t8 = 0; t8 < 8; ++t8) {
        u16x8 qv = *(const u16x8*)(q + t8 * 8);
        u16x8 kv = *(const u16x8*)(k + t8 * 8);
#pragma unroll
        for (int j = 0; j < 8; ++j) dot += bf2f(qv[j]) * bf2f(kv[j]);
    }
    return dot;
}

// ------------- per (b, masked-entity, q-group, rep) attention combine (bf16 inputs) -------------
// grid (E_, B_*4, 2). z=0: rep_h (me = outer i, q = inner j, row = me*E+q)
//                     z=1: rep_t (me = inner j, q = outer i, row = q*E+me)
__global__ __launch_bounds__(256) void combine_kernel(
    const short* __restrict__ Qb, const short* __restrict__ Kb,
    const short* __restrict__ VWb, const int* __restrict__ cnt,
    const int* __restrict__ mlist, float* __restrict__ out) {
    int z = blockIdx.z;
    const short* Q  = Qb  + (size_t)z * (B_ * E_ * D_);
    const short* K  = Kb  + (size_t)z * (B_ * M_ * D_);
    const short* VW = VWb + (size_t)z * (B_ * M_ * H_ * D_);
    int baserow = N_ + z * (E_ * E_);
    int me = blockIdx.x;
    int b = blockIdx.y >> 2, qg = blockIdx.y & 3;
    int qbase = qg * 16;
    int tid = threadIdx.x;
    int dq = tid & 63;
    __shared__ float sVW[2][H_ * D_];
    __shared__ float sS[16][H_][2];
    int c = cnt[b * E_ + me];
    const int* lst = mlist + (size_t)(b * E_ + me) * M_;

    if (c >= 1 && c <= 2) {
        for (int k = 0; k < c; ++k) {
            ushort4 v4 = *(const ushort4*)(VW + ((size_t)b * M_ + lst[k]) * (H_ * D_) + tid * 4);
            float4 f = make_float4(bf2f(v4.x), bf2f(v4.y), bf2f(v4.z), bf2f(v4.w));
            *(float4*)&sVW[k][tid * 4] = f;
        }
        if (tid < 128) {
            int k = tid & 1, hh = (tid >> 1) & 3, ql = tid >> 3;
            if (k < c) {
                const short* Qrow = Q + ((size_t)b * E_ + qbase + ql) * D_ + hh * DK_;
                const short* Krow = K + ((size_t)b * M_ + lst[k]) * D_ + hh * DK_;
                sS[ql][hh][k] = dot64_bf(Qrow, Krow) * 0.125f;
            }
        }
        __syncthreads();
        if (tid < 64) {
            int hh = tid & 3, ql = tid >> 2;
            float mx = sS[ql][hh][0];
            for (int k = 1; k < c; ++k) mx = fmaxf(mx, sS[ql][hh][k]);
            float w[2]; float sm = 0.f;
            for (int k = 0; k < c; ++k) { w[k] = __expf(sS[ql][hh][k] - mx); sm += w[k]; }
            float inv = 1.f / sm;
            for (int k = 0; k < c; ++k) sS[ql][hh][k] = w[k] * inv;
        }
        __syncthreads();
        for (int qq = tid >> 6; qq < 16; qq += 4) {
            float4 acc = make_float4(0.f, 0.f, 0.f, 0.f);
#pragma unroll
            for (int hh = 0; hh < H_; ++hh)
                for (int k = 0; k < c; ++k) {
                    float w = sS[qq][hh][k];
                    float4 v = *(const float4*)&sVW[k][hh * D_ + dq * 4];
                    acc.x += w * v.x; acc.y += w * v.y; acc.z += w * v.z; acc.w += w * v.w;
                }
            int q = qbase + qq;
            int row = z ? (q * E_ + me) : (me * E_ + q);
            *(float4*)&out[((size_t)b * OUTROWS + baserow + row) * D_ + dq * 4] = acc;
        }
    } else if (c == 0) {
        // fully masked -> uniform softmax over all M mentions
        float s = 0.f;
        for (int m = 0; m < M_; ++m)
            for (int hh = 0; hh < H_; ++hh)
                s += bf2f((unsigned short)VW[((size_t)b * M_ + m) * (H_ * D_) + hh * D_ + tid]);
        sVW[0][tid] = s * (1.0f / M_);
        __syncthreads();
        for (int qq = tid >> 6; qq < 16; qq += 4) {
            float4 v = *(const float4*)&sVW[0][dq * 4];
            int q = qbase + qq;
            int row = z ? (q * E_ + me) : (me * E_ + q);
            *(float4*)&out[((size_t)b * OUTROWS + baserow + row) * D_ + dq * 4] = v;
        }
    } else {
        // general fallback (correctness parachute)
        if (tid < 64) {
            int hh = tid & 3, ql = tid >> 2;
            const short* Qrow = Q + ((size_t)b * E_ + qbase + ql) * D_ + hh * DK_;
            float mx = -1e30f;
            for (int k = 0; k < c; ++k) {
                const short* Krow = K + ((size_t)b * M_ + lst[k]) * D_ + hh * DK_;
                mx = fmaxf(mx, dot64_bf(Qrow, Krow) * 0.125f);
            }
            float sm = 0.f;
            for (int k = 0; k < c; ++k) {
                const short* Krow = K + ((size_t)b * M_ + lst[k]) * D_ + hh * DK_;
                sm += __expf(dot64_bf(Qrow, Krow) * 0.125f - mx);
            }
            sS[ql][hh][0] = mx;
            sS[ql][hh][1] = sm;
        }
        __syncthreads();
        for (int qq = tid >> 6; qq < 16; qq += 4) {
            float4 acc = make_float4(0.f, 0.f, 0.f, 0.f);
            for (int hh = 0; hh < H_; ++hh) {
                float mx = sS[qq][hh][0], inv = 1.f / sS[qq][hh][1];
                const short* Qrow = Q + ((size_t)b * E_ + qbase + qq) * D_ + hh * DK_;
                for (int k = 0; k < c; ++k) {
                    const short* Krow = K + ((size_t)b * M_ + lst[k]) * D_ + hh * DK_;
                    float w = __expf(dot64_bf(Qrow, Krow) * 0.125f - mx) * inv;
                    ushort4 v4 = *(const ushort4*)(VW + ((size_t)b * M_ + lst[k]) * (H_ * D_) + hh * D_ + dq * 4);
                    acc.x += w * bf2f(v4.x); acc.y += w * bf2f(v4.y);
                    acc.z += w * bf2f(v4.z); acc.w += w * bf2f(v4.w);
                }
            }
            int q = qbase + qq;
            int row = z ? (q * E_ + me) : (me * E_ + q);
            *(float4*)&out[((size_t)b * OUTROWS + baserow + row) * D_ + dq * 4] = acc;
        }
    }
}

extern "C" void kernel_launch(void* const* d_in, const int* in_sizes, int n_in,
                              void* d_out, int out_size, void* d_ws, size_t ws_size,
                              hipStream_t stream) {
    const float* nodes     = (const float*)d_in[0];
    const float* adj       = (const float*)d_in[1];
    const float* mentions  = (const float*)d_in[2];
    const float* sentences = (const float*)d_in[3];
    const float* Wr0 = (const float*)d_in[4];
    const float* br0 = (const float*)d_in[5];
    const float* Wr1 = (const float*)d_in[6];
    const float* br1 = (const float*)d_in[7];
    const float* W00 = (const float*)d_in[8];
    const float* b00 = (const float*)d_in[9];
    const float* W01 = (const float*)d_in[10];
    const float* b01 = (const float*)d_in[11];
    const float* Wq_h = (const float*)d_in[12];
    const float* Wk_h = (const float*)d_in[13];
    const float* Wv_h = (const float*)d_in[14];
    const float* Wo_h = (const float*)d_in[15];
    const float* Wq_t = (const float*)d_in[16];
    const float* Wk_t = (const float*)d_in[17];
    const float* Wv_t = (const float*)d_in[18];
    const float* Wo_t = (const float*)d_in[19];
    const int* info_eid = (const int*)d_in[20];
    const int* info_sid = (const int*)d_in[21];
    float* out  = (float*)d_out;
    float* pool = (float*)d_ws;

    // ---- workspace layout (float offsets; shorts noted) ----
    short* xWb   = (short*)pool;                    // [6][1792][256] sh -> 1,376,256 fl
    short* VWb   = (short*)pool;                    // overlays dead xWb: [2][1024][1024] sh
    short* Qb    = (short*)(pool + 1048576);        // [2][8][64][256] sh (in xWb region)
    short* hb    = (short*)(pool + 1376256);        // [1792][256] sh -> 229,376 fl
    short* entsb = (short*)(pool + 1605632);        // [8][64][256] sh -> 65,536 fl
    short* KVb   = (short*)(pool + 1671168);        // [Kh,Kt,Vh,Vt] sh -> 524,288 fl
    short* nodesb= (short*)(pool + 2195456);        // [1792][320] sh -> 286,720 fl
    short* msrb  = (short*)(pool + 2482176);        // [1024][256] sh -> 131,072 fl
    short* mentb = (short*)(pool + 2613248);        // [1024][256] sh (adjacent to msrb)
    short* Wb    = (short*)(pool + 2744320);        // 1,802,240 sh -> 901,120 fl
    int*   elist = (int*)(pool + 3645440);          // 344,064
    float* evals = pool + 3989504;                  // 344,064
    int*   ecnt  = (int*)(pool + 4333568);          // 1,792
    float* den   = pool + 4335360;                  // 1,792
    int*   mcnt  = (int*)(pool + 4337152);          // 512
    int*   mlist = (int*)(pool + 4337664);          // 65,536 -> total 4,403,200 fl (17.6 MB)

    // packed bf16 weight offsets (shorts)
    short* W1t = Wb;                 // [6][256][320]
    short* W2t = Wb + 491520;        // [6][256][256]
    short* WKt = Wb + 884736;        // [2][256][256]
    short* WVt = Wb + 1146880;
    short* WQt = Wb + 1409024;
    short* WOt = Wb + 1671168;       // [8][256][64]

    // 1. fused preprocessing: pack weights | edge lists | mention lists | input cvt
    mega_pre<<<PRE_TOT, 256, 0, stream>>>(
        Wb, Wr0, W00, Wr1, W01, Wk_h, Wk_t, Wv_h, Wv_t, Wq_h, Wq_t, Wo_h, Wo_t,
        adj, ecnt, elist, evals, den, info_eid, mcnt, mlist,
        nodes, mentions, sentences, info_sid, nodesb, mentb, msrb);

    // 2. L1: z=0..4 -> xW slices, z=5 -> tb. Kloop=320 (both sides zero-padded).
    gemm_bf16<<<dim3(4, 28, 6), 256, 0, stream>>>(
        nodesb, 0, 0, 320, W1t, 81920, 0, 320,
        xWb, (long long)BN_ * D_, 0, D_,
        br0, D_, 5, b00, 320, 1);
    // 3. AxW layer 1 -> hb (bf16)
    axw_gather<<<BN_, 256, 0, stream>>>(xWb, ecnt, elist, evals, den,
                                        hb, nullptr, 0, nullptr);
    // 4. L2
    gemm_bf16<<<dim3(4, 28, 6), 256, 0, stream>>>(
        hb, 0, 0, D_, W2t, 65536, 0, D_,
        xWb, (long long)BN_ * D_, 0, D_,
        br1, D_, 5, b01, D_, 1);
    // 5. AxW layer 2 -> gcn_out (fp32, first N rows of out) + entsb (bf16)
    axw_gather<<<BN_, 256, 0, stream>>>(xWb, ecnt, elist, evals, den,
                                        nullptr, out, (long long)OUTROWS * D_, entsb);

    // 6. K+V projections merged: z1 = {K:msrb, V:mentb}, z2 = {h,t}
    gemm_bf16<<<dim3(4, 16, 4), 256, 0, stream>>>(
        msrb, 262144, 0, D_, WKt, 262144, 65536, D_,
        KVb, 524288, 262144, D_,
        nullptr, 0, 0, nullptr, D_, 2);
    // 7. VW[b,m,h,:] = V[b,m,h-slice] @ Wo[h-slice]; z = which*4 + h
    gemm_bf16<<<dim3(4, 16, 8), 256, 0, stream>>>(
        KVb + 524288, 262144, DK_, D_, WOt, 65536, 16384, DK_,
        VWb, (long long)B_ * M_ * H_ * D_, D_, H_ * D_,
        nullptr, 0, 0, nullptr, DK_, 4);
    // 8. Q projections from entsb: z = b*2 + which
    gemm_bf16<<<dim3(4, 1, 16), 256, 0, stream>>>(
        entsb, 16384, 0, D_, WQt, 0, 65536, D_,
        Qb, 16384, 131072, D_,
        nullptr, 0, 0, nullptr, D_, 2);

    // 9. merged attention combine: z=0 rep_h, z=1 rep_t
    combine_kernel<<<dim3(E_, B_ * 4, 2), 256, 0, stream>>>(Qb, KVb, VWb, mcnt, mlist, out);
}

// Round 9
// 106.695 us; speedup vs baseline: 5.2481x; 1.1425x over previous
//
#include <hip/hip_runtime.h>
#include <math.h>

#define B_ 8
#define N_ 224
#define E_ 64
#define M_ 128
#define S_ 32
#define D_ 256
#define IN_ 300
#define R_ 5
#define H_ 4
#define DK_ 64
#define OUTROWS (N_ + 2 * E_ * E_)   // 8416
#define CAP_ 192
#define BN_ (B_ * N_)                // 1792

typedef __attribute__((ext_vector_type(8))) short bf16x8;
typedef __attribute__((ext_vector_type(8))) unsigned short u16x8;
typedef __attribute__((ext_vector_type(4))) float f32x4;

__device__ inline short f2bf(float f) {
    union { float f; unsigned u; } x; x.f = f;
    unsigned u = x.u;
    unsigned r = (u + 0x7fffu + ((u >> 16) & 1u)) >> 16;
    return (short)r;
}
__device__ inline float bf2f(unsigned short s) {
    union { unsigned u; float f; } x; x.u = ((unsigned)s) << 16; return x.f;
}

// ================= mega preprocessing kernel (block-range dispatch) =================
#define PRE_PACK 1376
#define PRE_EDGE (PRE_PACK + BN_)     // 3168
#define PRE_ML   (PRE_EDGE + 2)       // 3170
#define CVT_N    573440               // 1792*320
#define CVT_M    262144               // 1024*256
#define PRE_TOT  (PRE_ML + 1072)

__global__ __launch_bounds__(256) void mega_pre(
    short* __restrict__ Wb,
    const float* Wr0, const float* W00, const float* Wr1, const float* W01,
    const float* Wkh, const float* Wkt, const float* Wvh, const float* Wvt,
    const float* Wqh, const float* Wqt, const float* Woh, const float* Wot,
    const float* __restrict__ adj, int* __restrict__ ecnt, int* __restrict__ elist,
    float* __restrict__ evals, float* __restrict__ den,
    const int* __restrict__ eid, int* __restrict__ mcnt, int* __restrict__ mlist,
    const float* __restrict__ nodes, const float* __restrict__ mentions,
    const float* __restrict__ sentences, const int* __restrict__ sid,
    short* __restrict__ nodesb, short* __restrict__ mentb, short* __restrict__ msrb) {
    __shared__ int smemi[528];
    __shared__ int wtot[4];
    __shared__ float wsum[4];
    int blk = blockIdx.x, tid = threadIdx.x;

    if (blk < PRE_PACK) {
        // ---- weight pack: bf16 transposed [n][k], 32x32 LDS transpose ----
        short (*T)[33] = (short(*)[33])smemi;
        int t = blk;
        const float* src; short* outp; int outld, klim, n0, k0;
        if (t < 480) {
            int z = t / 80, tt = t % 80;
            n0 = (tt & 7) * 32; k0 = (tt >> 3) * 32;
            outp = Wb + (size_t)z * 81920; outld = 320; klim = IN_;
            src = (z < 5) ? Wr0 + (size_t)z * IN_ * D_ : W00;
        } else if (t < 864) {
            int l = t - 480, z = l / 64, tt = l % 64;
            n0 = (tt & 7) * 32; k0 = (tt >> 3) * 32;
            outp = Wb + 491520 + (size_t)z * 65536; outld = 256; klim = 256;
            src = (z < 5) ? Wr1 + (size_t)z * D_ * D_ : W01;
        } else if (t < 992) {
            int l = t - 864, z = l / 64, tt = l % 64;
            n0 = (tt & 7) * 32; k0 = (tt >> 3) * 32;
            outp = Wb + 884736 + (size_t)z * 65536; outld = 256; klim = 256;
            src = z ? Wkt : Wkh;
        } else if (t < 1120) {
            int l = t - 992, z = l / 64, tt = l % 64;
            n0 = (tt & 7) * 32; k0 = (tt >> 3) * 32;
            outp = Wb + 1146880 + (size_t)z * 65536; outld = 256; klim = 256;
            src = z ? Wvt : Wvh;
        } else if (t < 1248) {
            int l = t - 1120, z = l / 64, tt = l % 64;
            n0 = (tt & 7) * 32; k0 = (tt >> 3) * 32;
            outp = Wb + 1409024 + (size_t)z * 65536; outld = 256; klim = 256;
            src = z ? Wqt : Wqh;
        } else {
            int l = t - 1248, z = l / 16, tt = l % 16;
            n0 = (tt & 7) * 32; k0 = (tt >> 3) * 32;
            outp = Wb + 1671168 + (size_t)z * 16384; outld = 64; klim = 64;
            int which = z >> 2, h = z & 3;
            src = (which ? Wot : Woh) + (size_t)(h * 64) * D_;
        }
        int tx = tid & 31, ty = tid >> 5;
#pragma unroll
        for (int i = 0; i < 4; ++i) {
            int k = k0 + ty + 8 * i;
            float v = (k < klim) ? src[(size_t)k * D_ + n0 + tx] : 0.f;
            T[tx][ty + 8 * i] = f2bf(v);
        }
        __syncthreads();
#pragma unroll
        for (int i = 0; i < 4; ++i) {
            int n = ty + 8 * i;
            outp[(size_t)(n0 + n) * outld + k0 + tx] = T[n][tx];
        }
    } else if (blk < PRE_EDGE) {
        // ---- edge lists + denoms: shfl-scan (1 barrier) ----
        int bn = blk - PRE_PACK;
        int b = bn / N_, n = bn % N_;
        int lane = tid & 63, wv4 = tid >> 6;
        int idxs[5]; float vals[5];
        int cloc = 0; float sloc = 0.f;
        for (int e = tid; e < R_ * N_; e += 256) {
            int r = e / N_, m = e % N_;
            float v = adj[(((size_t)(b * R_ + r)) * N_ + n) * N_ + m];
            if (v != 0.f) { idxs[cloc] = e; vals[cloc] = v; ++cloc; sloc += v; }
        }
        int v = cloc;
#pragma unroll
        for (int st = 1; st < 64; st <<= 1) {
            int o = __shfl_up(v, st, 64);
            if (lane >= st) v += o;
        }
        float fs = sloc;
#pragma unroll
        for (int st = 32; st > 0; st >>= 1) fs += __shfl_xor(fs, st, 64);
        if (lane == 63) wtot[wv4] = v;
        if (lane == 0)  wsum[wv4] = fs;
        __syncthreads();
        int woff = 0;
        for (int i = 0; i < wv4; ++i) woff += wtot[i];
        int off = woff + v - cloc;
        int total = wtot[0] + wtot[1] + wtot[2] + wtot[3];
        size_t base = (size_t)bn * CAP_;
        for (int i = 0; i < cloc; ++i) {
            int p = off + i;
            if (p < CAP_) { elist[base + p] = idxs[i]; evals[base + p] = vals[i]; }
        }
        if (tid == 0) {
            ecnt[bn] = total < CAP_ ? total : CAP_;
            den[bn] = wsum[0] + wsum[1] + wsum[2] + wsum[3] + 1.0f;
        }
    } else if (blk < PRE_ML) {
        int t = (blk - PRE_EDGE) * 256 + tid;
        if (t < B_ * E_) {
            int b = t / E_, i = t % E_;
            int c = 0;
            for (int m = 0; m < M_; ++m)
                if (eid[b * M_ + m] == i) mlist[(size_t)t * M_ + c++] = m;
            mcnt[t] = c;
        }
    } else {
        int idx = (blk - PRE_ML) * 1024 + tid * 4;
#pragma unroll
        for (int j = 0; j < 4; ++j) {
            int i = idx + j;
            if (i < CVT_N) {
                int row = i / 320, k = i % 320;
                nodesb[i] = (k < IN_) ? f2bf(nodes[(size_t)row * IN_ + k]) : (short)0;
            } else if (i < CVT_N + CVT_M) {
                int i2 = i - CVT_N;
                mentb[i2] = f2bf(mentions[i2]);
            } else {
                int i3 = i - CVT_N - CVT_M;
                int bm = i3 >> 8, d = i3 & 255;
                msrb[i3] = f2bf(sentences[(size_t)sid[bm] * D_ + d]);
            }
        }
    }
}

// ---------- AxW via edge gather (bf16 xW), 4 gather-waves + LDS reduce ----------
__global__ __launch_bounds__(256) void axw_gather(
    const short* __restrict__ xWb,
    const int* __restrict__ ecnt, const int* __restrict__ elist,
    const float* __restrict__ evals, const float* __restrict__ den,
    short* __restrict__ hb, float* __restrict__ out, long long out_bstride,
    short* __restrict__ entsb) {
    int bn = blockIdx.x;
    int b = bn / N_, n = bn % N_;
    int tid = threadIdx.x, wv = tid >> 6, dq = tid & 63;
    int c = ecnt[bn];
    const int* lst = elist + (size_t)bn * CAP_;
    const float* vls = evals + (size_t)bn * CAP_;
    float4 acc = make_float4(0.f, 0.f, 0.f, 0.f);
#pragma unroll 2
    for (int k = wv; k < c; k += 4) {
        int e = lst[k];
        float v = vls[k];
        int r = e / N_, m = e % N_;
        ushort4 x4 = *(const ushort4*)&xWb[((size_t)(r * BN_ + b * N_ + m)) * 256 + dq * 4];
        acc.x += v * bf2f(x4.x); acc.y += v * bf2f(x4.y);
        acc.z += v * bf2f(x4.z); acc.w += v * bf2f(x4.w);
    }
    __shared__ float4 red[4][64];
    red[wv][dq] = acc;
    __syncthreads();
    if (tid < 64) {
        float4 s0 = red[0][dq], s1 = red[1][dq], s2 = red[2][dq], s3 = red[3][dq];
        ushort4 t4 = *(const ushort4*)&xWb[((size_t)(5 * BN_ + bn)) * 256 + dq * 4];
        float inv = 1.f / den[bn];
        float4 o;
        o.x = fmaxf((s0.x + s1.x + s2.x + s3.x + bf2f(t4.x)) * inv, 0.f);
        o.y = fmaxf((s0.y + s1.y + s2.y + s3.y + bf2f(t4.y)) * inv, 0.f);
        o.z = fmaxf((s0.z + s1.z + s2.z + s3.z + bf2f(t4.z)) * inv, 0.f);
        o.w = fmaxf((s0.w + s1.w + s2.w + s3.w + bf2f(t4.w)) * inv, 0.f);
        if (hb) {
            ushort4 hw = { (unsigned short)f2bf(o.x), (unsigned short)f2bf(o.y),
                           (unsigned short)f2bf(o.z), (unsigned short)f2bf(o.w) };
            *(ushort4*)&hb[(size_t)bn * 256 + dq * 4] = hw;
        }
        if (out)
            *(float4*)&out[(size_t)b * out_bstride + (size_t)n * 256 + dq * 4] = o;
        if (entsb && n < E_) {
            ushort4 ew = { (unsigned short)f2bf(o.x), (unsigned short)f2bf(o.y),
                           (unsigned short)f2bf(o.z), (unsigned short)f2bf(o.w) };
            *(ushort4*)&entsb[((size_t)b * E_ + n) * 256 + dq * 4] = ew;
        }
    }
}

// ---------- multi-GEMM: per-blockIdx.z descriptor, all-bf16, tile 64x64, BK=64 ----------
struct GDesc {
    const short* A; const short* Bt; short* C; const float* bias;
    int lda, ldbk, ldc, Kloop, ny;
};
struct GTable { GDesc d[24]; };

__global__ __launch_bounds__(256) void gemm_multi(GTable T) {
    GDesc g = T.d[blockIdx.z];
    if ((int)blockIdx.y >= g.ny) return;

    __shared__ short As[64][72];
    __shared__ short Bs[64][72];
    int tid = threadIdx.x;
    int lane = tid & 63, wv = tid >> 6;
    int wr = wv >> 1, wc = wv & 1;
    int fr = lane & 15, fk = (lane >> 4) * 8;
    int row0 = blockIdx.y * 64, col0 = blockIdx.x * 64;
    int ar = tid >> 2, aq = (tid & 3) * 16;
    int bc = tid >> 2, bkq = (tid & 3) * 16;
    const short* Ap = g.A + (size_t)(row0 + ar) * g.lda;
    const short* Bp = g.Bt + (size_t)(col0 + bc) * g.ldbk;

    f32x4 acc00 = {0.f,0.f,0.f,0.f}, acc01 = acc00, acc10 = acc00, acc11 = acc00;

    for (int k0 = 0; k0 < g.Kloop; k0 += 64) {
        *(bf16x8*)&As[ar][aq]     = *(const bf16x8*)&Ap[k0 + aq];
        *(bf16x8*)&As[ar][aq + 8] = *(const bf16x8*)&Ap[k0 + aq + 8];
        *(bf16x8*)&Bs[bc][bkq]     = *(const bf16x8*)&Bp[k0 + bkq];
        *(bf16x8*)&Bs[bc][bkq + 8] = *(const bf16x8*)&Bp[k0 + bkq + 8];
        __syncthreads();
#pragma unroll
        for (int ks = 0; ks < 2; ++ks) {
            int ko = ks * 32 + fk;
            bf16x8 a0 = *(bf16x8*)&As[wr * 32 + fr][ko];
            bf16x8 a1 = *(bf16x8*)&As[wr * 32 + 16 + fr][ko];
            bf16x8 b0 = *(bf16x8*)&Bs[wc * 32 + fr][ko];
            bf16x8 b1 = *(bf16x8*)&Bs[wc * 32 + 16 + fr][ko];
            acc00 = __builtin_amdgcn_mfma_f32_16x16x32_bf16(a0, b0, acc00, 0, 0, 0);
            acc01 = __builtin_amdgcn_mfma_f32_16x16x32_bf16(a0, b1, acc01, 0, 0, 0);
            acc10 = __builtin_amdgcn_mfma_f32_16x16x32_bf16(a1, b0, acc10, 0, 0, 0);
            acc11 = __builtin_amdgcn_mfma_f32_16x16x32_bf16(a1, b1, acc11, 0, 0, 0);
        }
        __syncthreads();
    }

    int rbase = row0 + wr * 32 + (lane >> 4) * 4;
    int cbase = col0 + wc * 32 + fr;
    f32x4 accs[2][2] = {{acc00, acc01}, {acc10, acc11}};
#pragma unroll
    for (int mi = 0; mi < 2; ++mi) {
#pragma unroll
        for (int nj = 0; nj < 2; ++nj) {
            int cc = cbase + nj * 16;
            float bval = g.bias ? g.bias[cc] : 0.f;
#pragma unroll
            for (int r = 0; r < 4; ++r) {
                int cr = rbase + mi * 16 + r;
                g.C[(size_t)cr * g.ldc + cc] = f2bf(accs[mi][nj][r] + bval);
            }
        }
    }
}

__device__ inline float dot64_bf(const short* q, const short* k) {
    float dot = 0.f;
#pragma unroll
    for (int t8 = 0; t8 < 8; ++t8) {
        u16x8 qv = *(const u16x8*)(q + t8 * 8);
        u16x8 kv = *(const u16x8*)(k + t8 * 8);
#pragma unroll
        for (int j = 0; j < 8; ++j) dot += bf2f(qv[j]) * bf2f(kv[j]);
    }
    return dot;
}

// ------------- per (b, masked-entity, rep) attention combine: 64 q rows/block -------------
// grid (E_, B_, 2). z=0: rep_h (me = outer i, q = inner j, row = me*E+q)
//                   z=1: rep_t (me = inner j, q = outer i, row = q*E+me)
__global__ __launch_bounds__(256) void combine_kernel(
    const short* __restrict__ Qb, const short* __restrict__ Kb,
    const short* __restrict__ VWb, const int* __restrict__ cnt,
    const int* __restrict__ mlist, float* __restrict__ out) {
    int z = blockIdx.z;
    const short* Q  = Qb  + (size_t)z * (B_ * E_ * D_);
    const short* K  = Kb  + (size_t)z * (B_ * M_ * D_);
    const short* VW = VWb + (size_t)z * (B_ * M_ * H_ * D_);
    int baserow = N_ + z * (E_ * E_);
    int me = blockIdx.x;
    int b = blockIdx.y;
    int tid = threadIdx.x;
    int dq = tid & 63;
    __shared__ float sVW[2][H_ * D_];
    __shared__ float sS[E_][H_][2];
    int c = cnt[b * E_ + me];
    const int* lst = mlist + (size_t)(b * E_ + me) * M_;

    if (c >= 1 && c <= 2) {
        for (int k = 0; k < c; ++k) {
            ushort4 v4 = *(const ushort4*)(VW + ((size_t)b * M_ + lst[k]) * (H_ * D_) + tid * 4);
            *(float4*)&sVW[k][tid * 4] =
                make_float4(bf2f(v4.x), bf2f(v4.y), bf2f(v4.z), bf2f(v4.w));
        }
        for (int e = tid; e < E_ * H_ * 2; e += 256) {
            int k = e & 1, hh = (e >> 1) & 3, ql = e >> 3;
            if (k < c) {
                const short* Qrow = Q + ((size_t)b * E_ + ql) * D_ + hh * DK_;
                const short* Krow = K + ((size_t)b * M_ + lst[k]) * D_ + hh * DK_;
                sS[ql][hh][k] = dot64_bf(Qrow, Krow) * 0.125f;
            }
        }
        __syncthreads();
        {   // softmax: one (ql,hh) per thread (256 = 64*4)
            int hh = tid & 3, ql = tid >> 2;
            float mx = sS[ql][hh][0];
            for (int k = 1; k < c; ++k) mx = fmaxf(mx, sS[ql][hh][k]);
            float w[2]; float sm = 0.f;
            for (int k = 0; k < c; ++k) { w[k] = __expf(sS[ql][hh][k] - mx); sm += w[k]; }
            float inv = 1.f / sm;
            for (int k = 0; k < c; ++k) sS[ql][hh][k] = w[k] * inv;
        }
        __syncthreads();
        for (int qq = tid >> 6; qq < E_; qq += 4) {
            float4 acc = make_float4(0.f, 0.f, 0.f, 0.f);
#pragma unroll
            for (int hh = 0; hh < H_; ++hh)
                for (int k = 0; k < c; ++k) {
                    float w = sS[qq][hh][k];
                    float4 v = *(const float4*)&sVW[k][hh * D_ + dq * 4];
                    acc.x += w * v.x; acc.y += w * v.y; acc.z += w * v.z; acc.w += w * v.w;
                }
            int row = z ? (qq * E_ + me) : (me * E_ + qq);
            *(float4*)&out[((size_t)b * OUTROWS + baserow + row) * D_ + dq * 4] = acc;
        }
    } else if (c == 0) {
        // fully masked -> uniform softmax over all M mentions
        float s = 0.f;
        for (int m = 0; m < M_; ++m)
            for (int hh = 0; hh < H_; ++hh)
                s += bf2f((unsigned short)VW[((size_t)b * M_ + m) * (H_ * D_) + hh * D_ + tid]);
        sVW[0][tid] = s * (1.0f / M_);
        __syncthreads();
        for (int qq = tid >> 6; qq < E_; qq += 4) {
            float4 v = *(const float4*)&sVW[0][dq * 4];
            int row = z ? (qq * E_ + me) : (me * E_ + qq);
            *(float4*)&out[((size_t)b * OUTROWS + baserow + row) * D_ + dq * 4] = v;
        }
    } else {
        // general fallback (correctness parachute)
        {
            int hh = tid & 3, ql = tid >> 2;
            const short* Qrow = Q + ((size_t)b * E_ + ql) * D_ + hh * DK_;
            float mx = -1e30f;
            for (int k = 0; k < c; ++k) {
                const short* Krow = K + ((size_t)b * M_ + lst[k]) * D_ + hh * DK_;
                mx = fmaxf(mx, dot64_bf(Qrow, Krow) * 0.125f);
            }
            float sm = 0.f;
            for (int k = 0; k < c; ++k) {
                const short* Krow = K + ((size_t)b * M_ + lst[k]) * D_ + hh * DK_;
                sm += __expf(dot64_bf(Qrow, Krow) * 0.125f - mx);
            }
            sS[ql][hh][0] = mx;
            sS[ql][hh][1] = sm;
        }
        __syncthreads();
        for (int qq = tid >> 6; qq < E_; qq += 4) {
            float4 acc = make_float4(0.f, 0.f, 0.f, 0.f);
            for (int hh = 0; hh < H_; ++hh) {
                float mx = sS[qq][hh][0], inv = 1.f / sS[qq][hh][1];
                const short* Qrow = Q + ((size_t)b * E_ + qq) * D_ + hh * DK_;
                for (int k = 0; k < c; ++k) {
                    const short* Krow = K + ((size_t)b * M_ + lst[k]) * D_ + hh * DK_;
                    float w = __expf(dot64_bf(Qrow, Krow) * 0.125f - mx) * inv;
                    ushort4 v4 = *(const ushort4*)(VW + ((size_t)b * M_ + lst[k]) * (H_ * D_) + hh * D_ + dq * 4);
                    acc.x += w * bf2f(v4.x); acc.y += w * bf2f(v4.y);
                    acc.z += w * bf2f(v4.z); acc.w += w * bf2f(v4.w);
                }
            }
            int row = z ? (qq * E_ + me) : (me * E_ + qq);
            *(float4*)&out[((size_t)b * OUTROWS + baserow + row) * D_ + dq * 4] = acc;
        }
    }
}

extern "C" void kernel_launch(void* const* d_in, const int* in_sizes, int n_in,
                              void* d_out, int out_size, void* d_ws, size_t ws_size,
                              hipStream_t stream) {
    const float* nodes     = (const float*)d_in[0];
    const float* adj       = (const float*)d_in[1];
    const float* mentions  = (const float*)d_in[2];
    const float* sentences = (const float*)d_in[3];
    const float* Wr0 = (const float*)d_in[4];
    const float* br0 = (const float*)d_in[5];
    const float* Wr1 = (const float*)d_in[6];
    const float* br1 = (const float*)d_in[7];
    const float* W00 = (const float*)d_in[8];
    const float* b00 = (const float*)d_in[9];
    const float* W01 = (const float*)d_in[10];
    const float* b01 = (const float*)d_in[11];
    const float* Wq_h = (const float*)d_in[12];
    const float* Wk_h = (const float*)d_in[13];
    const float* Wv_h = (const float*)d_in[14];
    const float* Wo_h = (const float*)d_in[15];
    const float* Wq_t = (const float*)d_in[16];
    const float* Wk_t = (const float*)d_in[17];
    const float* Wv_t = (const float*)d_in[18];
    const float* Wo_t = (const float*)d_in[19];
    const int* info_eid = (const int*)d_in[20];
    const int* info_sid = (const int*)d_in[21];
    float* out  = (float*)d_out;
    float* pool = (float*)d_ws;

    // ---- workspace layout (float offsets; shorts noted) ----
    // xWb [6][1792][256] sh occupies shorts [0, 2752512).
    // AFTER axw2 consumes xWb, VWb ([2][1024][1024] sh = [0,2097152)) and
    // Qb (shorts [2097152, 2359296)) overlay the dead region.  Ordering
    // invariant: the VW/Q GEMM launch MUST follow axw_gather layer 2.
    short* xWb   = (short*)pool;
    short* VWb   = (short*)pool;
    short* Qb    = (short*)(pool + 1048576);
    short* hb    = (short*)(pool + 1376256);        // [1792][256] sh
    short* entsb = (short*)(pool + 1605632);        // [8][64][256] sh
    short* KVb   = (short*)(pool + 1671168);        // [Kh,Kt,Vh,Vt] sh
    short* nodesb= (short*)(pool + 2195456);        // [1792][320] sh
    short* msrb  = (short*)(pool + 2482176);        // [1024][256] sh
    short* mentb = (short*)(pool + 2613248);        // [1024][256] sh (adjacent to msrb)
    short* Wb    = (short*)(pool + 2744320);        // 1,802,240 sh
    int*   elist = (int*)(pool + 3645440);          // 344,064
    float* evals = pool + 3989504;                  // 344,064
    int*   ecnt  = (int*)(pool + 4333568);
    float* den   = pool + 4335360;
    int*   mcnt  = (int*)(pool + 4337152);
    int*   mlist = (int*)(pool + 4337664);          // -> total 4,403,200 fl (17.6 MB)

    short* W1t = Wb;                 // [6][256][320]
    short* W2t = Wb + 491520;        // [6][256][256]
    short* WKt = Wb + 884736;        // [Wkh, Wkt]
    short* WVt = Wb + 1146880;       // [Wvh, Wvt]
    short* WQt = Wb + 1409024;       // [Wqh, Wqt]
    short* WOt = Wb + 1671168;       // [8][256][64]

    // 1. fused preprocessing
    mega_pre<<<PRE_TOT, 256, 0, stream>>>(
        Wb, Wr0, W00, Wr1, W01, Wk_h, Wk_t, Wv_h, Wv_t, Wq_h, Wq_t, Wo_h, Wo_t,
        adj, ecnt, elist, evals, den, info_eid, mcnt, mlist,
        nodes, mentions, sentences, info_sid, nodesb, mentb, msrb);

    // 2. GEMM A: z 0..5 = L1 (nodes @ Wr0/W00), z 6..9 = K/V projections
    {
        GTable T = {};
        for (int z = 0; z < 6; ++z)
            T.d[z] = { nodesb, W1t + z * 81920, xWb + (size_t)z * BN_ * D_,
                       (z < 5) ? br0 + z * D_ : b00, 320, 320, D_, 320, 28 };
        for (int zp = 0; zp < 4; ++zp) {
            int half = zp >> 1, wt = zp & 1;  // half: 0=K(msrb,WKt), 1=V(mentb,WVt)
            T.d[6 + zp] = { msrb + half * 262144, (half ? WVt : WKt) + wt * 65536,
                            KVb + half * 524288 + wt * 262144,
                            nullptr, D_, D_, D_, D_, 16 };
        }
        gemm_multi<<<dim3(4, 28, 10), 256, 0, stream>>>(T);
    }
    // 3. AxW layer 1 -> hb (bf16)
    axw_gather<<<BN_, 256, 0, stream>>>(xWb, ecnt, elist, evals, den,
                                        hb, nullptr, 0, nullptr);
    // 4. GEMM B: z 0..5 = L2 only (h @ Wr1/W01) -> xWb
    {
        GTable T = {};
        for (int z = 0; z < 6; ++z)
            T.d[z] = { hb, W2t + z * 65536, xWb + (size_t)z * BN_ * D_,
                       (z < 5) ? br1 + z * D_ : b01, D_, D_, D_, D_, 28 };
        gemm_multi<<<dim3(4, 28, 6), 256, 0, stream>>>(T);
    }
    // 5. AxW layer 2 -> gcn_out (fp32 first N rows of out) + entsb (bf16).
    //    xWb is dead after this point; VWb/Qb may overlay it.
    axw_gather<<<BN_, 256, 0, stream>>>(xWb, ecnt, elist, evals, den,
                                        nullptr, out, (long long)OUTROWS * D_, entsb);
    // 6. GEMM C: z 0..7 = VW (V @ Wo per head), z 8..23 = Q projections
    {
        GTable T = {};
        for (int zp = 0; zp < 8; ++zp) {
            int which = zp >> 2, hh = zp & 3;
            T.d[zp] = { KVb + 524288 + which * 262144 + hh * DK_,
                        WOt + which * 65536 + hh * 16384,
                        VWb + (size_t)which * (B_ * M_ * H_ * D_) + hh * D_,
                        nullptr, D_, DK_, H_ * D_, DK_, 16 };
        }
        for (int z = 0; z < 16; ++z) {
            int b = z >> 1, which = z & 1;
            T.d[8 + z] = { entsb + b * 16384, WQt + which * 65536,
                           Qb + which * 131072 + b * 16384,
                           nullptr, D_, D_, D_, D_, 1 };
        }
        gemm_multi<<<dim3(4, 16, 24), 256, 0, stream>>>(T);
    }
    // 7. merged attention combine: z=0 rep_h, z=1 rep_t (64 q rows per block)
    combine_kernel<<<dim3(E_, B_, 2), 256, 0, stream>>>(Qb, KVb, VWb, mcnt, mlist, out);
}

// Round 10
// 100.079 us; speedup vs baseline: 5.5950x; 1.0661x over previous
//
#include <hip/hip_runtime.h>
#include <math.h>

#define B_ 8
#define N_ 224
#define E_ 64
#define M_ 128
#define S_ 32
#define D_ 256
#define IN_ 300
#define R_ 5
#define H_ 4
#define DK_ 64
#define OUTROWS (N_ + 2 * E_ * E_)   // 8416
#define CAP_ 192
#define BN_ (B_ * N_)                // 1792

typedef __attribute__((ext_vector_type(8))) short bf16x8;
typedef __attribute__((ext_vector_type(8))) unsigned short u16x8;
typedef __attribute__((ext_vector_type(4))) float f32x4;

__device__ inline short f2bf(float f) {
    union { float f; unsigned u; } x; x.f = f;
    unsigned u = x.u;
    unsigned r = (u + 0x7fffu + ((u >> 16) & 1u)) >> 16;
    return (short)r;
}
__device__ inline float bf2f(unsigned short s) {
    union { unsigned u; float f; } x; x.u = ((unsigned)s) << 16; return x.f;
}

// async global -> LDS, 16B per lane; lds base must be wave-uniform
__device__ inline void gload16(const void* g, void* l) {
    __builtin_amdgcn_global_load_lds(
        (const __attribute__((address_space(1))) unsigned int*)g,
        (__attribute__((address_space(3))) unsigned int*)l, 16, 0, 0);
}

// ================= mega preprocessing kernel (block-range dispatch) =================
#define PRE_PACK 1376
#define PRE_EDGE (PRE_PACK + BN_)     // 3168
#define PRE_ML   (PRE_EDGE + 2)       // 3170
#define CVT_N    573440               // 1792*320
#define CVT_M    262144               // 1024*256
#define PRE_TOT  (PRE_ML + 1072)

__global__ __launch_bounds__(256) void mega_pre(
    short* __restrict__ Wb,
    const float* Wr0, const float* W00, const float* Wr1, const float* W01,
    const float* Wkh, const float* Wkt, const float* Wvh, const float* Wvt,
    const float* Wqh, const float* Wqt, const float* Woh, const float* Wot,
    const float* __restrict__ adj, int* __restrict__ ecnt, int* __restrict__ elist,
    float* __restrict__ evals, float* __restrict__ den,
    const int* __restrict__ eid, int* __restrict__ mcnt, int* __restrict__ mlist,
    const float* __restrict__ nodes, const float* __restrict__ mentions,
    const float* __restrict__ sentences, const int* __restrict__ sid,
    short* __restrict__ nodesb, short* __restrict__ mentb, short* __restrict__ msrb) {
    __shared__ int smemi[528];
    __shared__ int wtot[4];
    __shared__ float wsum[4];
    int blk = blockIdx.x, tid = threadIdx.x;

    if (blk < PRE_PACK) {
        // ---- weight pack: bf16 transposed [n][k], 32x32 LDS transpose ----
        short (*T)[33] = (short(*)[33])smemi;
        int t = blk;
        const float* src; short* outp; int outld, klim, n0, k0;
        if (t < 480) {
            int z = t / 80, tt = t % 80;
            n0 = (tt & 7) * 32; k0 = (tt >> 3) * 32;
            outp = Wb + (size_t)z * 81920; outld = 320; klim = IN_;
            src = (z < 5) ? Wr0 + (size_t)z * IN_ * D_ : W00;
        } else if (t < 864) {
            int l = t - 480, z = l / 64, tt = l % 64;
            n0 = (tt & 7) * 32; k0 = (tt >> 3) * 32;
            outp = Wb + 491520 + (size_t)z * 65536; outld = 256; klim = 256;
            src = (z < 5) ? Wr1 + (size_t)z * D_ * D_ : W01;
        } else if (t < 992) {
            int l = t - 864, z = l / 64, tt = l % 64;
            n0 = (tt & 7) * 32; k0 = (tt >> 3) * 32;
            outp = Wb + 884736 + (size_t)z * 65536; outld = 256; klim = 256;
            src = z ? Wkt : Wkh;
        } else if (t < 1120) {
            int l = t - 992, z = l / 64, tt = l % 64;
            n0 = (tt & 7) * 32; k0 = (tt >> 3) * 32;
            outp = Wb + 1146880 + (size_t)z * 65536; outld = 256; klim = 256;
            src = z ? Wvt : Wvh;
        } else if (t < 1248) {
            int l = t - 1120, z = l / 64, tt = l % 64;
            n0 = (tt & 7) * 32; k0 = (tt >> 3) * 32;
            outp = Wb + 1409024 + (size_t)z * 65536; outld = 256; klim = 256;
            src = z ? Wqt : Wqh;
        } else {
            int l = t - 1248, z = l / 16, tt = l % 16;
            n0 = (tt & 7) * 32; k0 = (tt >> 3) * 32;
            outp = Wb + 1671168 + (size_t)z * 16384; outld = 64; klim = 64;
            int which = z >> 2, h = z & 3;
            src = (which ? Wot : Woh) + (size_t)(h * 64) * D_;
        }
        int tx = tid & 31, ty = tid >> 5;
#pragma unroll
        for (int i = 0; i < 4; ++i) {
            int k = k0 + ty + 8 * i;
            float v = (k < klim) ? src[(size_t)k * D_ + n0 + tx] : 0.f;
            T[tx][ty + 8 * i] = f2bf(v);
        }
        __syncthreads();
#pragma unroll
        for (int i = 0; i < 4; ++i) {
            int n = ty + 8 * i;
            outp[(size_t)(n0 + n) * outld + k0 + tx] = T[n][tx];
        }
    } else if (blk < PRE_EDGE) {
        // ---- edge lists + denoms: shfl-scan (1 barrier) ----
        int bn = blk - PRE_PACK;
        int b = bn / N_, n = bn % N_;
        int lane = tid & 63, wv4 = tid >> 6;
        int idxs[5]; float vals[5];
        int cloc = 0; float sloc = 0.f;
        for (int e = tid; e < R_ * N_; e += 256) {
            int r = e / N_, m = e % N_;
            float v = adj[(((size_t)(b * R_ + r)) * N_ + n) * N_ + m];
            if (v != 0.f) { idxs[cloc] = e; vals[cloc] = v; ++cloc; sloc += v; }
        }
        int v = cloc;
#pragma unroll
        for (int st = 1; st < 64; st <<= 1) {
            int o = __shfl_up(v, st, 64);
            if (lane >= st) v += o;
        }
        float fs = sloc;
#pragma unroll
        for (int st = 32; st > 0; st >>= 1) fs += __shfl_xor(fs, st, 64);
        if (lane == 63) wtot[wv4] = v;
        if (lane == 0)  wsum[wv4] = fs;
        __syncthreads();
        int woff = 0;
        for (int i = 0; i < wv4; ++i) woff += wtot[i];
        int off = woff + v - cloc;
        int total = wtot[0] + wtot[1] + wtot[2] + wtot[3];
        size_t base = (size_t)bn * CAP_;
        for (int i = 0; i < cloc; ++i) {
            int p = off + i;
            if (p < CAP_) { elist[base + p] = idxs[i]; evals[base + p] = vals[i]; }
        }
        if (tid == 0) {
            ecnt[bn] = total < CAP_ ? total : CAP_;
            den[bn] = wsum[0] + wsum[1] + wsum[2] + wsum[3] + 1.0f;
        }
    } else if (blk < PRE_ML) {
        int t = (blk - PRE_EDGE) * 256 + tid;
        if (t < B_ * E_) {
            int b = t / E_, i = t % E_;
            int c = 0;
            for (int m = 0; m < M_; ++m)
                if (eid[b * M_ + m] == i) mlist[(size_t)t * M_ + c++] = m;
            mcnt[t] = c;
        }
    } else {
        int idx = (blk - PRE_ML) * 1024 + tid * 4;
#pragma unroll
        for (int j = 0; j < 4; ++j) {
            int i = idx + j;
            if (i < CVT_N) {
                int row = i / 320, k = i % 320;
                nodesb[i] = (k < IN_) ? f2bf(nodes[(size_t)row * IN_ + k]) : (short)0;
            } else if (i < CVT_N + CVT_M) {
                int i2 = i - CVT_N;
                mentb[i2] = f2bf(mentions[i2]);
            } else {
                int i3 = i - CVT_N - CVT_M;
                int bm = i3 >> 8, d = i3 & 255;
                msrb[i3] = f2bf(sentences[(size_t)sid[bm] * D_ + d]);
            }
        }
    }
}

// ---------- AxW via edge gather (bf16 xW), 4 gather-waves + LDS reduce ----------
__global__ __launch_bounds__(256) void axw_gather(
    const short* __restrict__ xWb,
    const int* __restrict__ ecnt, const int* __restrict__ elist,
    const float* __restrict__ evals, const float* __restrict__ den,
    short* __restrict__ hb, float* __restrict__ out, long long out_bstride,
    short* __restrict__ entsb) {
    int bn = blockIdx.x;
    int b = bn / N_, n = bn % N_;
    int tid = threadIdx.x, wv = tid >> 6, dq = tid & 63;
    int c = ecnt[bn];
    const int* lst = elist + (size_t)bn * CAP_;
    const float* vls = evals + (size_t)bn * CAP_;
    float4 acc = make_float4(0.f, 0.f, 0.f, 0.f);
#pragma unroll 2
    for (int k = wv; k < c; k += 4) {
        int e = lst[k];
        float v = vls[k];
        int r = e / N_, m = e % N_;
        ushort4 x4 = *(const ushort4*)&xWb[((size_t)(r * BN_ + b * N_ + m)) * 256 + dq * 4];
        acc.x += v * bf2f(x4.x); acc.y += v * bf2f(x4.y);
        acc.z += v * bf2f(x4.z); acc.w += v * bf2f(x4.w);
    }
    __shared__ float4 red[4][64];
    red[wv][dq] = acc;
    __syncthreads();
    if (tid < 64) {
        float4 s0 = red[0][dq], s1 = red[1][dq], s2 = red[2][dq], s3 = red[3][dq];
        ushort4 t4 = *(const ushort4*)&xWb[((size_t)(5 * BN_ + bn)) * 256 + dq * 4];
        float inv = 1.f / den[bn];
        float4 o;
        o.x = fmaxf((s0.x + s1.x + s2.x + s3.x + bf2f(t4.x)) * inv, 0.f);
        o.y = fmaxf((s0.y + s1.y + s2.y + s3.y + bf2f(t4.y)) * inv, 0.f);
        o.z = fmaxf((s0.z + s1.z + s2.z + s3.z + bf2f(t4.z)) * inv, 0.f);
        o.w = fmaxf((s0.w + s1.w + s2.w + s3.w + bf2f(t4.w)) * inv, 0.f);
        if (hb) {
            ushort4 hw = { (unsigned short)f2bf(o.x), (unsigned short)f2bf(o.y),
                           (unsigned short)f2bf(o.z), (unsigned short)f2bf(o.w) };
            *(ushort4*)&hb[(size_t)bn * 256 + dq * 4] = hw;
        }
        if (out)
            *(float4*)&out[(size_t)b * out_bstride + (size_t)n * 256 + dq * 4] = o;
        if (entsb && n < E_) {
            ushort4 ew = { (unsigned short)f2bf(o.x), (unsigned short)f2bf(o.y),
                           (unsigned short)f2bf(o.z), (unsigned short)f2bf(o.w) };
            *(ushort4*)&entsb[((size_t)b * E_ + n) * 256 + dq * 4] = ew;
        }
    }
}

// ---------- multi-GEMM: per-blockIdx.z descriptor, all-bf16, tile 64x64, BK=64 ----------
// Staging via global_load_lds (direct-to-LDS, 16B/lane). LDS layout is LINEAR
// [64][64] shorts; the 16B slot is XOR-swizzled by (row&7) on the GLOBAL source
// address (pre-swizzle) and identically on the fragment read (rule: both sides,
// same involution; LDS dest stays linear as global_load_lds requires).
struct GDesc {
    const short* A; const short* Bt; short* C; const float* bias;
    int lda, ldbk, ldc, Kloop, ny;
};
struct GTable { GDesc d[24]; };

__global__ __launch_bounds__(256) void gemm_multi(GTable T) {
    GDesc g = T.d[blockIdx.z];
    if ((int)blockIdx.y >= g.ny) return;

    __shared__ short As[64 * 64];
    __shared__ short Bs[64 * 64];
    int tid = threadIdx.x;
    int lane = tid & 63, wv = tid >> 6;
    int wr = wv >> 1, wc = wv & 1;
    int fr = lane & 15;
    int so = lane >> 4;              // fragment slot sub-index (0..3)
    int row0 = blockIdx.y * 64, col0 = blockIdx.x * 64;

    // staging geometry: each wave stages chunks c0,c1 (1KB each = 8 rows x 128B)
    int l8 = lane >> 3;              // row within chunk (0..7)
    int sl = (lane & 7) ^ l8;        // pre-swizzled 16B slot
    int c0 = 2 * wv, c1 = c0 + 1;
    int ra0 = row0 + 8 * c0 + l8, ra1 = row0 + 8 * c1 + l8;
    int rb0 = col0 + 8 * c0 + l8, rb1 = col0 + 8 * c1 + l8;

    f32x4 acc00 = {0.f,0.f,0.f,0.f}, acc01 = acc00, acc10 = acc00, acc11 = acc00;

    int rA0 = wr * 32 + fr, rA1 = rA0 + 16;
    int rB0 = wc * 32 + fr, rB1 = rB0 + 16;
    int sw = fr & 7;

    for (int k0 = 0; k0 < g.Kloop; k0 += 64) {
        gload16(&g.A [(size_t)ra0 * g.lda  + k0 + sl * 8], &As[c0 * 512]);
        gload16(&g.A [(size_t)ra1 * g.lda  + k0 + sl * 8], &As[c1 * 512]);
        gload16(&g.Bt[(size_t)rb0 * g.ldbk + k0 + sl * 8], &Bs[c0 * 512]);
        gload16(&g.Bt[(size_t)rb1 * g.ldbk + k0 + sl * 8], &Bs[c1 * 512]);
        __syncthreads();
#pragma unroll
        for (int ks = 0; ks < 2; ++ks) {
            int s = ks * 4 + so;
            bf16x8 a0 = *(bf16x8*)&As[rA0 * 64 + ((s ^ sw) << 3)];
            bf16x8 a1 = *(bf16x8*)&As[rA1 * 64 + ((s ^ sw) << 3)];
            bf16x8 b0 = *(bf16x8*)&Bs[rB0 * 64 + ((s ^ sw) << 3)];
            bf16x8 b1 = *(bf16x8*)&Bs[rB1 * 64 + ((s ^ sw) << 3)];
            acc00 = __builtin_amdgcn_mfma_f32_16x16x32_bf16(a0, b0, acc00, 0, 0, 0);
            acc01 = __builtin_amdgcn_mfma_f32_16x16x32_bf16(a0, b1, acc01, 0, 0, 0);
            acc10 = __builtin_amdgcn_mfma_f32_16x16x32_bf16(a1, b0, acc10, 0, 0, 0);
            acc11 = __builtin_amdgcn_mfma_f32_16x16x32_bf16(a1, b1, acc11, 0, 0, 0);
        }
        __syncthreads();
    }

    int rbase = row0 + wr * 32 + (lane >> 4) * 4;
    int cbase = col0 + wc * 32 + fr;
    f32x4 accs[2][2] = {{acc00, acc01}, {acc10, acc11}};
#pragma unroll
    for (int mi = 0; mi < 2; ++mi) {
#pragma unroll
        for (int nj = 0; nj < 2; ++nj) {
            int cc = cbase + nj * 16;
            float bval = g.bias ? g.bias[cc] : 0.f;
#pragma unroll
            for (int r = 0; r < 4; ++r) {
                int cr = rbase + mi * 16 + r;
                g.C[(size_t)cr * g.ldc + cc] = f2bf(accs[mi][nj][r] + bval);
            }
        }
    }
}

__device__ inline float dot64_bf(const short* q, const short* k) {
    float dot = 0.f;
#pragma unroll
    for (int t8 = 0; t8 < 8; ++t8) {
        u16x8 qv = *(const u16x8*)(q + t8 * 8);
        u16x8 kv = *(const u16x8*)(k + t8 * 8);
#pragma unroll
        for (int j = 0; j < 8; ++j) dot += bf2f(qv[j]) * bf2f(kv[j]);
    }
    return dot;
}

// ------------- per (b, masked-entity, rep) attention combine: 64 q rows/block -------------
// grid (E_, B_, 2). z=0: rep_h (me = outer i, q = inner j, row = me*E+q)
//                   z=1: rep_t (me = inner j, q = outer i, row = q*E+me)
__global__ __launch_bounds__(256) void combine_kernel(
    const short* __restrict__ Qb, const short* __restrict__ Kb,
    const short* __restrict__ VWb, const int* __restrict__ cnt,
    const int* __restrict__ mlist, float* __restrict__ out) {
    int z = blockIdx.z;
    const short* Q  = Qb  + (size_t)z * (B_ * E_ * D_);
    const short* K  = Kb  + (size_t)z * (B_ * M_ * D_);
    const short* VW = VWb + (size_t)z * (B_ * M_ * H_ * D_);
    int baserow = N_ + z * (E_ * E_);
    int me = blockIdx.x;
    int b = blockIdx.y;
    int tid = threadIdx.x;
    int dq = tid & 63;
    __shared__ float sVW[2][H_ * D_];
    __shared__ float sS[E_][H_][2];
    int c = cnt[b * E_ + me];
    const int* lst = mlist + (size_t)(b * E_ + me) * M_;

    if (c >= 1 && c <= 2) {
        for (int k = 0; k < c; ++k) {
            ushort4 v4 = *(const ushort4*)(VW + ((size_t)b * M_ + lst[k]) * (H_ * D_) + tid * 4);
            *(float4*)&sVW[k][tid * 4] =
                make_float4(bf2f(v4.x), bf2f(v4.y), bf2f(v4.z), bf2f(v4.w));
        }
        for (int e = tid; e < E_ * H_ * 2; e += 256) {
            int k = e & 1, hh = (e >> 1) & 3, ql = e >> 3;
            if (k < c) {
                const short* Qrow = Q + ((size_t)b * E_ + ql) * D_ + hh * DK_;
                const short* Krow = K + ((size_t)b * M_ + lst[k]) * D_ + hh * DK_;
                sS[ql][hh][k] = dot64_bf(Qrow, Krow) * 0.125f;
            }
        }
        __syncthreads();
        {   // softmax: one (ql,hh) per thread (256 = 64*4)
            int hh = tid & 3, ql = tid >> 2;
            float mx = sS[ql][hh][0];
            for (int k = 1; k < c; ++k) mx = fmaxf(mx, sS[ql][hh][k]);
            float w[2]; float sm = 0.f;
            for (int k = 0; k < c; ++k) { w[k] = __expf(sS[ql][hh][k] - mx); sm += w[k]; }
            float inv = 1.f / sm;
            for (int k = 0; k < c; ++k) sS[ql][hh][k] = w[k] * inv;
        }
        __syncthreads();
        for (int qq = tid >> 6; qq < E_; qq += 4) {
            float4 acc = make_float4(0.f, 0.f, 0.f, 0.f);
#pragma unroll
            for (int hh = 0; hh < H_; ++hh)
                for (int k = 0; k < c; ++k) {
                    float w = sS[qq][hh][k];
                    float4 v = *(const float4*)&sVW[k][hh * D_ + dq * 4];
                    acc.x += w * v.x; acc.y += w * v.y; acc.z += w * v.z; acc.w += w * v.w;
                }
            int row = z ? (qq * E_ + me) : (me * E_ + qq);
            *(float4*)&out[((size_t)b * OUTROWS + baserow + row) * D_ + dq * 4] = acc;
        }
    } else if (c == 0) {
        // fully masked -> uniform softmax over all M mentions
        float s = 0.f;
        for (int m = 0; m < M_; ++m)
            for (int hh = 0; hh < H_; ++hh)
                s += bf2f((unsigned short)VW[((size_t)b * M_ + m) * (H_ * D_) + hh * D_ + tid]);
        sVW[0][tid] = s * (1.0f / M_);
        __syncthreads();
        for (int qq = tid >> 6; qq < E_; qq += 4) {
            float4 v = *(const float4*)&sVW[0][dq * 4];
            int row = z ? (qq * E_ + me) : (me * E_ + qq);
            *(float4*)&out[((size_t)b * OUTROWS + baserow + row) * D_ + dq * 4] = v;
        }
    } else {
        // general fallback (correctness parachute)
        {
            int hh = tid & 3, ql = tid >> 2;
            const short* Qrow = Q + ((size_t)b * E_ + ql) * D_ + hh * DK_;
            float mx = -1e30f;
            for (int k = 0; k < c; ++k) {
                const short* Krow = K + ((size_t)b * M_ + lst[k]) * D_ + hh * DK_;
                mx = fmaxf(mx, dot64_bf(Qrow, Krow) * 0.125f);
            }
            float sm = 0.f;
            for (int k = 0; k < c; ++k) {
                const short* Krow = K + ((size_t)b * M_ + lst[k]) * D_ + hh * DK_;
                sm += __expf(dot64_bf(Qrow, Krow) * 0.125f - mx);
            }
            sS[ql][hh][0] = mx;
            sS[ql][hh][1] = sm;
        }
        __syncthreads();
        for (int qq = tid >> 6; qq < E_; qq += 4) {
            float4 acc = make_float4(0.f, 0.f, 0.f, 0.f);
            for (int hh = 0; hh < H_; ++hh) {
                float mx = sS[qq][hh][0], inv = 1.f / sS[qq][hh][1];
                const short* Qrow = Q + ((size_t)b * E_ + qq) * D_ + hh * DK_;
                for (int k = 0; k < c; ++k) {
                    const short* Krow = K + ((size_t)b * M_ + lst[k]) * D_ + hh * DK_;
                    float w = __expf(dot64_bf(Qrow, Krow) * 0.125f - mx) * inv;
                    ushort4 v4 = *(const ushort4*)(VW + ((size_t)b * M_ + lst[k]) * (H_ * D_) + hh * D_ + dq * 4);
                    acc.x += w * bf2f(v4.x); acc.y += w * bf2f(v4.y);
                    acc.z += w * bf2f(v4.z); acc.w += w * bf2f(v4.w);
                }
            }
            int row = z ? (qq * E_ + me) : (me * E_ + qq);
            *(float4*)&out[((size_t)b * OUTROWS + baserow + row) * D_ + dq * 4] = acc;
        }
    }
}

extern "C" void kernel_launch(void* const* d_in, const int* in_sizes, int n_in,
                              void* d_out, int out_size, void* d_ws, size_t ws_size,
                              hipStream_t stream) {
    const float* nodes     = (const float*)d_in[0];
    const float* adj       = (const float*)d_in[1];
    const float* mentions  = (const float*)d_in[2];
    const float* sentences = (const float*)d_in[3];
    const float* Wr0 = (const float*)d_in[4];
    const float* br0 = (const float*)d_in[5];
    const float* Wr1 = (const float*)d_in[6];
    const float* br1 = (const float*)d_in[7];
    const float* W00 = (const float*)d_in[8];
    const float* b00 = (const float*)d_in[9];
    const float* W01 = (const float*)d_in[10];
    const float* b01 = (const float*)d_in[11];
    const float* Wq_h = (const float*)d_in[12];
    const float* Wk_h = (const float*)d_in[13];
    const float* Wv_h = (const float*)d_in[14];
    const float* Wo_h = (const float*)d_in[15];
    const float* Wq_t = (const float*)d_in[16];
    const float* Wk_t = (const float*)d_in[17];
    const float* Wv_t = (const float*)d_in[18];
    const float* Wo_t = (const float*)d_in[19];
    const int* info_eid = (const int*)d_in[20];
    const int* info_sid = (const int*)d_in[21];
    float* out  = (float*)d_out;
    float* pool = (float*)d_ws;

    // ---- workspace layout (float offsets; shorts noted) ----
    // xWb [6][1792][256] sh occupies shorts [0, 2752512).
    // AFTER axw2 consumes xWb, VWb ([2][1024][1024] sh = [0,2097152)) and
    // Qb (shorts [2097152, 2359296)) overlay the dead region.  Ordering
    // invariant: the VW/Q GEMM launch MUST follow axw_gather layer 2.
    short* xWb   = (short*)pool;
    short* VWb   = (short*)pool;
    short* Qb    = (short*)(pool + 1048576);
    short* hb    = (short*)(pool + 1376256);        // [1792][256] sh
    short* entsb = (short*)(pool + 1605632);        // [8][64][256] sh
    short* KVb   = (short*)(pool + 1671168);        // [Kh,Kt,Vh,Vt] sh
    short* nodesb= (short*)(pool + 2195456);        // [1792][320] sh
    short* msrb  = (short*)(pool + 2482176);        // [1024][256] sh
    short* mentb = (short*)(pool + 2613248);        // [1024][256] sh (adjacent to msrb)
    short* Wb    = (short*)(pool + 2744320);        // 1,802,240 sh
    int*   elist = (int*)(pool + 3645440);          // 344,064
    float* evals = pool + 3989504;                  // 344,064
    int*   ecnt  = (int*)(pool + 4333568);
    float* den   = pool + 4335360;
    int*   mcnt  = (int*)(pool + 4337152);
    int*   mlist = (int*)(pool + 4337664);          // -> total 4,403,200 fl (17.6 MB)

    short* W1t = Wb;                 // [6][256][320]
    short* W2t = Wb + 491520;        // [6][256][256]
    short* WKt = Wb + 884736;        // [Wkh, Wkt]
    short* WVt = Wb + 1146880;       // [Wvh, Wvt]
    short* WQt = Wb + 1409024;       // [Wqh, Wqt]
    short* WOt = Wb + 1671168;       // [8][256][64]

    // 1. fused preprocessing
    mega_pre<<<PRE_TOT, 256, 0, stream>>>(
        Wb, Wr0, W00, Wr1, W01, Wk_h, Wk_t, Wv_h, Wv_t, Wq_h, Wq_t, Wo_h, Wo_t,
        adj, ecnt, elist, evals, den, info_eid, mcnt, mlist,
        nodes, mentions, sentences, info_sid, nodesb, mentb, msrb);

    // 2. GEMM A: z 0..5 = L1 (nodes @ Wr0/W00), z 6..9 = K/V projections
    {
        GTable T = {};
        for (int z = 0; z < 6; ++z)
            T.d[z] = { nodesb, W1t + z * 81920, xWb + (size_t)z * BN_ * D_,
                       (z < 5) ? br0 + z * D_ : b00, 320, 320, D_, 320, 28 };
        for (int zp = 0; zp < 4; ++zp) {
            int half = zp >> 1, wt = zp & 1;  // half: 0=K(msrb,WKt), 1=V(mentb,WVt)
            T.d[6 + zp] = { msrb + half * 262144, (half ? WVt : WKt) + wt * 65536,
                            KVb + half * 524288 + wt * 262144,
                            nullptr, D_, D_, D_, D_, 16 };
        }
        gemm_multi<<<dim3(4, 28, 10), 256, 0, stream>>>(T);
    }
    // 3. AxW layer 1 -> hb (bf16)
    axw_gather<<<BN_, 256, 0, stream>>>(xWb, ecnt, elist, evals, den,
                                        hb, nullptr, 0, nullptr);
    // 4. GEMM B: z 0..5 = L2 only (h @ Wr1/W01) -> xWb
    {
        GTable T = {};
        for (int z = 0; z < 6; ++z)
            T.d[z] = { hb, W2t + z * 65536, xWb + (size_t)z * BN_ * D_,
                       (z < 5) ? br1 + z * D_ : b01, D_, D_, D_, D_, 28 };
        gemm_multi<<<dim3(4, 28, 6), 256, 0, stream>>>(T);
    }
    // 5. AxW layer 2 -> gcn_out (fp32 first N rows of out) + entsb (bf16).
    //    xWb is dead after this point; VWb/Qb may overlay it.
    axw_gather<<<BN_, 256, 0, stream>>>(xWb, ecnt, elist, evals, den,
                                        nullptr, out, (long long)OUTROWS * D_, entsb);
    // 6. GEMM C: z 0..7 = VW (V @ Wo per head), z 8..23 = Q projections
    {
        GTable T = {};
        for (int zp = 0; zp < 8; ++zp) {
            int which = zp >> 2, hh = zp & 3;
            T.d[zp] = { KVb + 524288 + which * 262144 + hh * DK_,
                        WOt + which * 65536 + hh * 16384,
                        VWb + (size_t)which * (B_ * M_ * H_ * D_) + hh * D_,
                        nullptr, D_, DK_, H_ * D_, DK_, 16 };
        }
        for (int z = 0; z < 16; ++z) {
            int b = z >> 1, which = z & 1;
            T.d[8 + z] = { entsb + b * 16384, WQt + which * 65536,
                           Qb + which * 131072 + b * 16384,
                           nullptr, D_, D_, D_, D_, 1 };
        }
        gemm_multi<<<dim3(4, 16, 24), 256, 0, stream>>>(T);
    }
    // 7. merged attention combine: z=0 rep_h, z=1 rep_t (64 q rows per block)
    combine_kernel<<<dim3(E_, B_, 2), 256, 0, stream>>>(Qb, KVb, VWb, mcnt, mlist, out);
}